// Round 6
// baseline (11839.233 us; speedup 1.0000x reference)
//
#include <hip/hip_runtime.h>

// LSTMConditioned: conv-encoder + attention-LSTM (T=64) + MDN head.
// N=128, T=64, HID=512, COMB=1024, ATT=128, K=20, D=2, FMAP=64, L=196, ODIM=121.
// Recurrence: ONE persistent kernel, 256 blocks x 512 threads.
// NO global barrier: per-sample-group (32 samples) flag counters, 4 independent pipelines.
// 128 attention blocks (1 sample each) + 128 gates blocks (32 samples x 16 h-cols, weights in regs).

#define TN 128
#define TT 64
#define NB 256

typedef __attribute__((ext_vector_type(4))) float f32x4;
typedef __attribute__((ext_vector_type(8))) short bf16x8;

__device__ __forceinline__ float fsigm(float x){ return __builtin_amdgcn_rcpf(1.0f + __expf(-x)); }
__device__ __forceinline__ float ftanh(float x){ return 1.0f - 2.0f*__builtin_amdgcn_rcpf(1.0f + __expf(2.0f*x)); }
__device__ __forceinline__ unsigned short f2bf(float f){
  unsigned int u = __float_as_uint(f);
  u += 0x7fffu + ((u >> 16) & 1u);
  return (unsigned short)(u >> 16);
}
__device__ __forceinline__ float b2f(unsigned short u){ return __uint_as_float(((unsigned)u)<<16); }

// ---------------- conv1 (direct, small) ----------------
__global__ __launch_bounds__(256) void k_conv1(const float* __restrict__ xc, const float* __restrict__ w,
                                               const float* __restrict__ b, float* __restrict__ c1){
  int idx = blockIdx.x*256 + threadIdx.x;
  if (idx >= TN*16*784) return;
  int p = idx % 784, oc = (idx/784) & 15, n = idx/(784*16);
  int py = p/28, px = p%28;
  const float* src = xc + n*784;
  float acc = b[oc];
  #pragma unroll
  for (int ky=0;ky<3;ky++){
    int iy = py+ky-1; if (iy<0||iy>=28) continue;
    #pragma unroll
    for (int kx=0;kx<3;kx++){
      int ix = px+kx-1; if (ix<0||ix>=28) continue;
      acc += (src[iy*28+ix]-0.0243f)*(1.0f/0.1383f) * w[oc*9+ky*3+kx];
    }
  }
  c1[idx] = fmaxf(acc, 0.0f);
}

// ---------------- im2col for conv2 ----------------
__global__ __launch_bounds__(256) void k_im2col2(const float* __restrict__ c1, unsigned short* __restrict__ a2){
  int idx = blockIdx.x*256 + threadIdx.x;   // 62720*256 = 100352*160
  int k = idx % 160, r = idx / 160;
  unsigned short v = 0;
  if (k < 144){
    int ic = k/9, rem = k - ic*9, ky = rem/3, kx = rem - ky*3;
    int p = r % 784, n = r / 784;
    int py = p/28, px = p%28;
    int iy = py+ky-1, ix = px+kx-1;
    if (iy>=0 && iy<28 && ix>=0 && ix<28) v = f2bf(c1[(n*16+ic)*784 + iy*28+ix]);
  }
  a2[idx] = v;
}

// ---------------- conv2 GEMM ----------------
__global__ __launch_bounds__(256) void k_gconv2(const unsigned short* __restrict__ a2,
    const unsigned short* __restrict__ w2b, const float* __restrict__ b2,
    unsigned short* __restrict__ c2bf){
  int mbase = blockIdx.x*128;           // 784 blocks
  int tid = threadIdx.x, w = tid>>6, l = tid&63;
  int lr = l&15, lk = (l>>4)*8;
  __shared__ unsigned short at[128*168];
  {
    int row = tid>>1, off = (tid&1)*80;
    const unsigned short* sp = a2 + (size_t)(mbase+row)*160 + off;
    #pragma unroll
    for (int j=0;j<10;j++) *(float4*)&at[row*168 + off + j*8] = *(const float4*)(sp + j*8);
  }
  __syncthreads();
  f32x4 acc[2][2];
  #pragma unroll
  for (int mi=0;mi<2;mi++){ acc[mi][0]=(f32x4){0,0,0,0}; acc[mi][1]=(f32x4){0,0,0,0}; }
  for (int kt=0; kt<5; ++kt){
    bf16x8 b0 = *(const bf16x8*)(w2b + (0*16+lr)*160 + kt*32 + lk);
    bf16x8 b1 = *(const bf16x8*)(w2b + (1*16+lr)*160 + kt*32 + lk);
    #pragma unroll
    for (int mi=0;mi<2;mi++){
      bf16x8 afrag = *(const bf16x8*)&at[((2*w+mi)*16+lr)*168 + kt*32 + lk];
      acc[mi][0] = __builtin_amdgcn_mfma_f32_16x16x32_bf16(afrag, b0, acc[mi][0], 0,0,0);
      acc[mi][1] = __builtin_amdgcn_mfma_f32_16x16x32_bf16(afrag, b1, acc[mi][1], 0,0,0);
    }
  }
  #pragma unroll
  for (int mi=0;mi<2;mi++){
    #pragma unroll
    for (int j=0;j<2;j++){
      int oc = j*16 + lr;
      float bb = b2[oc];
      #pragma unroll
      for (int i=0;i<4;i++){
        int r = mbase + (2*w+mi)*16 + (l>>4)*4 + i;
        c2bf[(size_t)r*32 + oc] = f2bf(fmaxf(acc[mi][j][i] + bb, 0.0f));
      }
    }
  }
}

// ---------------- im2col for conv3 (stride 2) ----------------
__global__ __launch_bounds__(256) void k_im2col3(const unsigned short* __restrict__ c2bf, unsigned short* __restrict__ a3){
  int idx = blockIdx.x*256 + threadIdx.x;   // 31360*256 = 25088*320
  int k = idx % 320, r = idx / 320;
  unsigned short v = 0;
  if (k < 288){
    int ic = k/9, rem = k - ic*9, ky = rem/3, kx = rem - ky*3;
    int p = r % 196, n = r / 196;
    int py = p/14, px = p%14;
    int iy = 2*py+ky-1, ix = 2*px+kx-1;
    if (iy>=0 && iy<28 && ix>=0 && ix<28) v = c2bf[(size_t)(n*784 + iy*28+ix)*32 + ic];
  }
  a3[idx] = v;
}

// ---------------- conv3 GEMM: afbf[n][f][l] (bf16) + abf[r][f] (bf16) ----------------
__global__ __launch_bounds__(256) void k_gconv3(const unsigned short* __restrict__ a3,
    const unsigned short* __restrict__ w3b, const float* __restrict__ b3,
    unsigned short* __restrict__ afbf, unsigned short* __restrict__ abf){
  int mbase = blockIdx.x*128;           // 196 blocks
  int tid = threadIdx.x, w = tid>>6, l = tid&63;
  int lr = l&15, lk = (l>>4)*8;
  __shared__ unsigned short at[128*168];
  f32x4 acc[2][4];
  #pragma unroll
  for (int mi=0;mi<2;mi++)
    #pragma unroll
    for (int j=0;j<4;j++) acc[mi][j]=(f32x4){0,0,0,0};
  for (int kt2=0; kt2<2; ++kt2){
    {
      int row = tid>>1, off = (tid&1)*80;
      const unsigned short* sp = a3 + (size_t)(mbase+row)*320 + kt2*160 + off;
      #pragma unroll
      for (int j=0;j<10;j++) *(float4*)&at[row*168 + off + j*8] = *(const float4*)(sp + j*8);
    }
    __syncthreads();
    for (int kt=0; kt<5; ++kt){
      #pragma unroll
      for (int mi=0;mi<2;mi++){
        bf16x8 afrag = *(const bf16x8*)&at[((2*w+mi)*16+lr)*168 + kt*32 + lk];
        #pragma unroll
        for (int j=0;j<4;j++){
          bf16x8 bf = *(const bf16x8*)(w3b + (size_t)(j*16+lr)*320 + kt2*160 + kt*32 + lk);
          acc[mi][j] = __builtin_amdgcn_mfma_f32_16x16x32_bf16(afrag, bf, acc[mi][j], 0,0,0);
        }
      }
    }
    __syncthreads();
  }
  #pragma unroll
  for (int mi=0;mi<2;mi++){
    #pragma unroll
    for (int j=0;j<4;j++){
      int oc = j*16 + lr;
      float bb = b3[oc];
      #pragma unroll
      for (int i=0;i<4;i++){
        int r = mbase + (2*w+mi)*16 + (l>>4)*4 + i;
        int n = r/196, p = r - n*196;
        float v = ftanh(acc[mi][j][i] + bb);
        unsigned short vb16 = f2bf(v);
        afbf[(size_t)(n*64+oc)*196 + p] = vb16;
        abf[(size_t)r*64 + oc] = vb16;
      }
    }
  }
}

__global__ __launch_bounds__(64) void k_amean(const unsigned short* __restrict__ afbf, float* __restrict__ amean){
  int n = blockIdx.x, f = threadIdx.x;
  const unsigned short* row = afbf + (size_t)(n*64+f)*196;
  float s = 0;
  for (int l=0;l<196;l++) s += b2f(row[l]);
  amean[n*64+f] = s * (1.0f/196.0f);
}

// ---------------- embeddings / init ----------------
__global__ __launch_bounds__(256) void k_embed(const float* __restrict__ x, const float* __restrict__ start,
    const float* __restrict__ xw, const float* __restrict__ xb,
    const float* __restrict__ sw, const float* __restrict__ sb,
    float* __restrict__ xe, float* __restrict__ se){
  int idx = blockIdx.x*256 + threadIdx.x;
  if (idx < TN*TT*16){
    int j = idx & 15, t = (idx>>4) & 63, n = idx>>10;
    float acc = xb[j];
    if (t > 0){
      const float* xp = x + (n*TT + t-1)*2;
      acc += xp[0]*xw[j*2] + xp[1]*xw[j*2+1];
    }
    xe[idx] = ftanh(acc);
  } else if (idx < TN*TT*16 + TN*16){
    int k2 = idx - TN*TT*16;
    int j = k2 & 15, n = k2 >> 4;
    float acc = sb[j] + start[n*2]*sw[j*2] + start[n*2+1]*sw[j*2+1];
    se[k2] = ftanh(acc);
  }
}

// init h/c, bf16 h, and zero the flag arrays
__global__ __launch_bounds__(256) void k_init(const float* __restrict__ amean, const float* __restrict__ se,
    const float* __restrict__ w, const float* __restrict__ b,
    float* __restrict__ hbuf, float* __restrict__ cbuf, unsigned short* __restrict__ hbf,
    int* __restrict__ zcnt, int* __restrict__ hcnt){
  int idx = blockIdx.x*256 + threadIdx.x;
  if (idx < TN*1024){
    int o = idx & 1023, n = idx >> 10;
    const float* wr = w + o*80;
    float acc = b[o];
    for (int k2=0;k2<64;k2++) acc += amean[n*64+k2]*wr[k2];
    for (int k2=0;k2<16;k2++) acc += se[n*16+k2]*wr[64+k2];
    float v = ftanh(acc);
    if (o & 1) cbuf[n*512 + (o>>1)] = v;
    else { hbuf[n*512 + (o>>1)] = v; hbf[n*512 + (o>>1)] = f2bf(v); }
  } else {
    int f = idx - TN*1024;
    if (f < 4096) zcnt[f] = 0;
    else if (f < 8192) hcnt[f-4096] = 0;
  }
}

// ---------------- weight prep ----------------
__global__ __launch_bounds__(256) void k_prep(
    const float* __restrict__ Whh, const float* __restrict__ Wih,
    const float* __restrict__ bih, const float* __restrict__ bhh,
    const float* __restrict__ comb_w, const float* __restrict__ out_w, const float* __restrict__ out_b,
    const float* __restrict__ Uw, const float* __restrict__ beta_w, const float* __restrict__ Ww,
    const float* __restrict__ conv2_w, const float* __restrict__ conv3_w,
    unsigned short* __restrict__ whh_bf, unsigned short* __restrict__ wih_bf, float* __restrict__ gbias,
    unsigned short* __restrict__ cwbf, unsigned short* __restrict__ owbf, float* __restrict__ obias,
    unsigned short* __restrict__ uwbf, unsigned short* __restrict__ betabf, unsigned short* __restrict__ wwbf,
    unsigned short* __restrict__ w2b, unsigned short* __restrict__ w3b){
  int idx = blockIdx.x*256 + threadIdx.x;
  if (idx < 1048576){ whh_bf[idx] = f2bf(Whh[idx]); return; }
  idx -= 1048576;
  if (idx < 196608){ int o = idx/96, k2 = idx%96; wih_bf[idx] = (k2<80) ? f2bf(Wih[o*80+k2]) : (unsigned short)0; return; }
  idx -= 196608;
  if (idx < 2048){ gbias[idx] = bih[idx]+bhh[idx]; return; }
  idx -= 2048;
  if (idx < 622592){ cwbf[idx] = f2bf(comb_w[idx]); return; }
  idx -= 622592;
  if (idx < 131072){ int o = idx>>10, k2 = idx & 1023; owbf[idx] = (o<121)? f2bf(out_w[o*1024+k2]) : (unsigned short)0; return; }
  idx -= 131072;
  if (idx < 128){ obias[idx] = (idx<121)? out_b[idx] : 0.0f; return; }
  idx -= 128;
  if (idx < 65536){ uwbf[idx] = f2bf(Uw[idx]); return; }
  idx -= 65536;
  if (idx < 32768){ betabf[idx] = f2bf(beta_w[idx]); return; }
  idx -= 32768;
  if (idx < 8192){ wwbf[idx] = f2bf(Ww[idx]); return; }
  idx -= 8192;
  if (idx < 5120){ int o = idx/160, k2 = idx - o*160; w2b[idx] = (k2<144)? f2bf(conv2_w[o*144+k2]) : (unsigned short)0; return; }
  idx -= 5120;
  if (idx < 20480){ int o = idx/320, k2 = idx - o*320; w3b[idx] = (k2<288)? f2bf(conv3_w[o*288+k2]) : (unsigned short)0; return; }
}

// ---------------- W_a = a @ Ww.T + Wb (MFMA), stored bf16 [n][l][att] ----------------
__global__ __launch_bounds__(256) void k_wa(const unsigned short* __restrict__ abf,
    const unsigned short* __restrict__ wwbf, const float* __restrict__ Wb,
    unsigned short* __restrict__ wabf){
  int mbase = blockIdx.x*128;
  int tid = threadIdx.x, w = tid>>6, l = tid&63;
  int lr = l & 15, lk = (l>>4)*8;
  __shared__ unsigned short at[128*40];
  f32x4 acc[8][2];
  #pragma unroll
  for (int m=0;m<8;m++){ acc[m][0] = (f32x4){0,0,0,0}; acc[m][1] = (f32x4){0,0,0,0}; }
  for (int kt=0; kt<2; ++kt){
    int row = tid>>1, half = (tid&1)*16;
    const unsigned short* sp = abf + (mbase+row)*64 + kt*32 + half;
    *(float4*)&at[row*40 + half]     = *(const float4*)sp;
    *(float4*)&at[row*40 + half + 8] = *(const float4*)(sp + 8);
    __syncthreads();
    bf16x8 b0 = *(const bf16x8*)(wwbf + ((2*w+0)*16 + lr)*64 + kt*32 + lk);
    bf16x8 b1 = *(const bf16x8*)(wwbf + ((2*w+1)*16 + lr)*64 + kt*32 + lk);
    #pragma unroll
    for (int m=0;m<8;m++){
      bf16x8 afrag = *(const bf16x8*)&at[(m*16+lr)*40 + lk];
      acc[m][0] = __builtin_amdgcn_mfma_f32_16x16x32_bf16(afrag, b0, acc[m][0], 0,0,0);
      acc[m][1] = __builtin_amdgcn_mfma_f32_16x16x32_bf16(afrag, b1, acc[m][1], 0,0,0);
    }
    __syncthreads();
  }
  #pragma unroll
  for (int m=0;m<8;m++){
    #pragma unroll
    for (int j=0;j<2;j++){
      int att = (2*w+j)*16 + lr;
      float wb = Wb[att];
      #pragma unroll
      for (int i=0;i<4;i++){
        int arow = mbase + m*16 + (l>>4)*4 + i;
        int n = arow/196, l2 = arow - n*196;
        wabf[((size_t)n*196 + l2)*128 + att] = f2bf(acc[m][j][i] + wb);
      }
    }
  }
}

// ---------------- flag sync helpers ----------------
__device__ __forceinline__ void waitflag(int* f, int target){
  if (threadIdx.x == 0){
    while (__hip_atomic_load(f, __ATOMIC_ACQUIRE, __HIP_MEMORY_SCOPE_AGENT) < target)
      __builtin_amdgcn_s_sleep(1);
  }
  __syncthreads();
  __threadfence();
}
__device__ __forceinline__ void signalflag(int* f){
  __threadfence();
  __syncthreads();
  if (threadIdx.x == 0)
    __hip_atomic_fetch_add(f, 1, __ATOMIC_RELEASE, __HIP_MEMORY_SCOPE_AGENT);
}

// ---------------- persistent recurrence kernel (flag-pipelined, no global barrier) ----------------
__global__ __launch_bounds__(512) void k_loop(
    const unsigned short* __restrict__ uwbf, const float* __restrict__ Ub,
    const unsigned short* __restrict__ betabf, const float* __restrict__ beta_b,
    const float* __restrict__ vw, const float* __restrict__ vb,
    const unsigned short* __restrict__ wabf, const unsigned short* __restrict__ afbf,
    const float* __restrict__ xe,
    const unsigned short* __restrict__ whh_bf, const unsigned short* __restrict__ wih_bf,
    const float* __restrict__ gbias,
    float* __restrict__ hbuf, float* __restrict__ cbuf,
    unsigned short* __restrict__ hbf,
    unsigned short* __restrict__ ubf, unsigned short* __restrict__ cbf,
    int* __restrict__ zcnt, int* __restrict__ hcnt)
{
  const int bid = blockIdx.x, tid = threadIdx.x;
  __shared__ __align__(16) unsigned short at[32*616];   // gates A-tile; attention aliases scratch here
  __shared__ __align__(16) float gsh[8][32][16];

  if (bid < TN){
    // ============ attention role: sample n = bid, group mq = n>>5 ============
    const int n = bid, mq = n >> 5;
    float* hs   = (float*)at;            // [512)
    float* Uh   = hs + 512;              // [128)
    float* vws  = hs + 640;              // [128)
    float* bsig = hs + 768;              // [64)
    float* ew   = hs + 832;              // [196)
    float* red  = hs + 1028;             // [16)
    float* zs   = hs + 1044;             // [64)
    float* up   = hs + 1108;             // [4][128)
    float* qp8  = hs + 1620;             // [8][64)
    float* ep2  = hs + 2132;             // [256][2)
    if (tid < 128) vws[tid] = vw[tid];
    const float vb0 = vb[0];
    for (int t = 0; t < TT; ++t){
      if (t > 0) waitflag(&hcnt[((t-1)*4+mq)*16], 32);
      hs[tid] = hbuf[n*512 + tid];
      __syncthreads();
      // Uh partials: thread = (att, k-quarter)
      {
        int att = tid & 127, q = tid >> 7;
        const unsigned short* uw = uwbf + att*512 + q*128;
        const float* hh = hs + q*128;
        float acc = 0.f;
        #pragma unroll 4
        for (int k=0;k<128;k+=8){
          bf16x8 v = *(const bf16x8*)(uw + k);
          acc += hh[k+0]*b2f(v[0]) + hh[k+1]*b2f(v[1]) + hh[k+2]*b2f(v[2]) + hh[k+3]*b2f(v[3])
               + hh[k+4]*b2f(v[4]) + hh[k+5]*b2f(v[5]) + hh[k+6]*b2f(v[6]) + hh[k+7]*b2f(v[7]);
        }
        up[q*128 + att] = acc;
      }
      // beta partials: thread = (f, k-eighth)
      {
        int f = tid & 63, q = tid >> 6;
        const unsigned short* bw = betabf + f*512 + q*64;
        const float* hh = hs + q*64;
        float acc = 0.f;
        #pragma unroll 4
        for (int k=0;k<64;k+=8){
          bf16x8 v = *(const bf16x8*)(bw + k);
          acc += hh[k+0]*b2f(v[0]) + hh[k+1]*b2f(v[1]) + hh[k+2]*b2f(v[2]) + hh[k+3]*b2f(v[3])
               + hh[k+4]*b2f(v[4]) + hh[k+5]*b2f(v[5]) + hh[k+6]*b2f(v[6]) + hh[k+7]*b2f(v[7]);
        }
        qp8[q*64 + f] = acc;
      }
      __syncthreads();
      if (tid < 128) Uh[tid] = Ub[tid] + up[0*128+tid]+up[1*128+tid]+up[2*128+tid]+up[3*128+tid];
      else if (tid < 192){
        int f = tid-128;
        bsig[f] = fsigm(beta_b[f] + qp8[0*64+f]+qp8[1*64+f]+qp8[2*64+f]+qp8[3*64+f]
                                  + qp8[4*64+f]+qp8[5*64+f]+qp8[6*64+f]+qp8[7*64+f]);
      }
      __syncthreads();
      // e partials: thread = (l, att-half)
      {
        int l = tid >> 1, half = tid & 1;
        float acc = 0.f;
        if (l < 196){
          const unsigned short* wr = wabf + ((size_t)n*196 + l)*128 + half*64;
          const float* uh = Uh + half*64;
          const float* vv = vws + half*64;
          #pragma unroll 2
          for (int k=0;k<64;k+=8){
            bf16x8 wv = *(const bf16x8*)(wr + k);
            acc += vv[k+0]*ftanh(b2f(wv[0]) + uh[k+0]) + vv[k+1]*ftanh(b2f(wv[1]) + uh[k+1])
                 + vv[k+2]*ftanh(b2f(wv[2]) + uh[k+2]) + vv[k+3]*ftanh(b2f(wv[3]) + uh[k+3])
                 + vv[k+4]*ftanh(b2f(wv[4]) + uh[k+4]) + vv[k+5]*ftanh(b2f(wv[5]) + uh[k+5])
                 + vv[k+6]*ftanh(b2f(wv[6]) + uh[k+6]) + vv[k+7]*ftanh(b2f(wv[7]) + uh[k+7]);
          }
        }
        ep2[l*2 + half] = acc;
      }
      __syncthreads();
      float ev = -1e30f;
      if (tid < 196) ev = vb0 + ep2[tid*2] + ep2[tid*2+1];
      float m = ev;
      #pragma unroll
      for (int off=32; off>0; off>>=1) m = fmaxf(m, __shfl_xor(m, off));
      if ((tid&63)==0) red[tid>>6] = m;
      __syncthreads();
      float mx = fmaxf(fmaxf(red[0],red[1]), fmaxf(red[2],red[3]));
      float ex = (tid<196) ? __expf(ev - mx) : 0.0f;
      float ss = ex;
      #pragma unroll
      for (int off=32; off>0; off>>=1) ss += __shfl_xor(ss, off);
      if ((tid&63)==0) red[8+(tid>>6)] = ss;
      if (tid<196) ew[tid] = ex;
      __syncthreads();
      float inv = __builtin_amdgcn_rcpf(red[8]+red[9]+red[10]+red[11]);
      // z partials: thread = (f, l-chunk of 25)
      {
        int f = tid & 63, q = tid >> 6;
        int l0 = q*25, l1 = (l0+25 < 196) ? l0+25 : 196;
        const unsigned short* an = afbf + (size_t)n*12544 + f*196;
        float acc = 0.f;
        for (int l2=l0; l2<l1; l2++) acc += ew[l2]*b2f(an[l2]);
        qp8[q*64 + f] = acc;
      }
      __syncthreads();
      if (tid < 64) zs[tid] = bsig[tid]*(qp8[0*64+tid]+qp8[1*64+tid]+qp8[2*64+tid]+qp8[3*64+tid]
                                       + qp8[4*64+tid]+qp8[5*64+tid]+qp8[6*64+tid]+qp8[7*64+tid])*inv;
      __syncthreads();
      if (tid < 96){
        unsigned short val;
        if (tid < 16) val = f2bf(xe[(n*TT + t)*16 + tid]);
        else if (tid < 80) val = f2bf(zs[tid-16]);
        else val = 0;
        ubf[n*96 + tid] = val;
        if (tid >= 16 && tid < 80) cbf[(size_t)(n*TT + t)*608 + 512 + (tid-16)] = val;
      }
      signalflag(&zcnt[(t*4+mq)*16]);
    }
  } else {
    // ============ gates role: col-slice b (16 h-cols), sample-group mq (32 samples) ============
    const int gid = bid - TN;
    const int b = gid & 31, mq = gid >> 5;
    const int w = tid>>6, l = tid&63, lr = l&15, lk = (l>>4)*8;
    const int g = w>>1, kh = w&1;
    const int ow = g*512 + b*16 + lr;
    // preload this wave's weight fragments into registers (once)
    bf16x8 wreg[10];
    if (kh==0){
      #pragma unroll
      for (int i=0;i<10;i++) wreg[i] = *(const bf16x8*)(whh_bf + (size_t)ow*512 + i*32 + lk);
    } else {
      #pragma unroll
      for (int i=0;i<6;i++) wreg[i] = *(const bf16x8*)(whh_bf + (size_t)ow*512 + (10+i)*32 + lk);
      #pragma unroll
      for (int i=0;i<3;i++) wreg[6+i] = *(const bf16x8*)(wih_bf + (size_t)ow*96 + i*32 + lk);
    }
    for (int t = 0; t < TT; ++t){
      if (t > 0) waitflag(&hcnt[((t-1)*4+mq)*16], 32);
      // stage h-part of A (32 samples x 512 cols, bf16)
      for (int i = tid; i < 2048; i += 512){
        int row = i>>6, f8 = i&63;
        *(float4*)&at[row*616 + f8*8] = *(const float4*)(hbf + (size_t)(mq*32+row)*512 + f8*8);
      }
      __syncthreads();
      f32x4 acc0={0,0,0,0}, acc1={0,0,0,0};
      if (kh==0){
        #pragma unroll
        for (int i=0;i<10;i++){
          bf16x8 a0 = *(const bf16x8*)&at[(     lr)*616 + i*32 + lk];
          bf16x8 a1 = *(const bf16x8*)&at[(16 + lr)*616 + i*32 + lk];
          acc0 = __builtin_amdgcn_mfma_f32_16x16x32_bf16(a0, wreg[i], acc0, 0,0,0);
          acc1 = __builtin_amdgcn_mfma_f32_16x16x32_bf16(a1, wreg[i], acc1, 0,0,0);
        }
      } else {
        #pragma unroll
        for (int i=0;i<6;i++){
          bf16x8 a0 = *(const bf16x8*)&at[(     lr)*616 + (10+i)*32 + lk];
          bf16x8 a1 = *(const bf16x8*)&at[(16 + lr)*616 + (10+i)*32 + lk];
          acc0 = __builtin_amdgcn_mfma_f32_16x16x32_bf16(a0, wreg[i], acc0, 0,0,0);
          acc1 = __builtin_amdgcn_mfma_f32_16x16x32_bf16(a1, wreg[i], acc1, 0,0,0);
        }
      }
      // wait for z/u of this group, stage u-part (96 cols)
      waitflag(&zcnt[(t*4+mq)*16], 32);
      if (tid < 384){
        int row = tid/12, f8 = tid - row*12;
        *(float4*)&at[row*616 + 512 + f8*8] = *(const float4*)(ubf + (mq*32+row)*96 + f8*8);
      }
      __syncthreads();
      if (kh==1){
        #pragma unroll
        for (int i=0;i<3;i++){
          bf16x8 a0 = *(const bf16x8*)&at[(     lr)*616 + (16+i)*32 + lk];
          bf16x8 a1 = *(const bf16x8*)&at[(16 + lr)*616 + (16+i)*32 + lk];
          acc0 = __builtin_amdgcn_mfma_f32_16x16x32_bf16(a0, wreg[6+i], acc0, 0,0,0);
          acc1 = __builtin_amdgcn_mfma_f32_16x16x32_bf16(a1, wreg[6+i], acc1, 0,0,0);
        }
      }
      #pragma unroll
      for (int i=0;i<4;i++){
        gsh[w][(l>>4)*4 + i][lr]      = acc0[i];
        gsh[w][16 + (l>>4)*4 + i][lr] = acc1[i];
      }
      __syncthreads();
      // cell update: 512 cells (32 samples x 16 cols), 1 per thread
      {
        int nn = tid>>4, j = tid&15;
        int n2 = mq*32 + nn, hidx = b*16 + j;
        float gi = gsh[0][nn][j] + gsh[1][nn][j] + gbias[        b*16 + j];
        float gf = gsh[2][nn][j] + gsh[3][nn][j] + gbias[1*512 + b*16 + j];
        float gg2= gsh[4][nn][j] + gsh[5][nn][j] + gbias[2*512 + b*16 + j];
        float go = gsh[6][nn][j] + gsh[7][nn][j] + gbias[3*512 + b*16 + j];
        float cc = cbuf[n2*512 + hidx];
        float cs = fsigm(gf)*cc + fsigm(gi)*ftanh(gg2);
        float h  = fsigm(go)*ftanh(cs);
        cbuf[n2*512 + hidx] = cs;
        hbuf[n2*512 + hidx] = h;
        unsigned short hb = f2bf(h);
        hbf[n2*512 + hidx] = hb;
        cbf[(size_t)(n2*TT + t)*608 + hidx] = hb;
      }
      __syncthreads();
      signalflag(&hcnt[(t*4+mq)*16]);
    }
  }
}

// ---------------- comb-input xe/se slices ----------------
__global__ __launch_bounds__(256) void k_cbf_xs(const float* __restrict__ xe, const float* __restrict__ se,
                                                unsigned short* __restrict__ cbf){
  int idx = blockIdx.x*256 + threadIdx.x;
  if (idx >= TN*TT*32) return;
  int j = idx & 31, r = idx >> 5;
  int n = r >> 6;
  if (j < 16) cbf[(size_t)r*608 + 576 + j] = f2bf(xe[r*16 + j]);
  else        cbf[(size_t)r*608 + 592 + (j-16)] = f2bf(se[n*16 + (j-16)]);
}

// ---------------- comb GEMM ----------------
__global__ __launch_bounds__(256) void k_comb(const unsigned short* __restrict__ cbf,
    const unsigned short* __restrict__ cwbf, const float* __restrict__ comb_b,
    unsigned short* __restrict__ ybf){
  int mbase = blockIdx.x*128, obase = blockIdx.y*128;
  int tid = threadIdx.x, w = tid>>6, l = tid&63;
  int lr = l&15, lk = (l>>4)*8;
  __shared__ unsigned short at[128*40];
  f32x4 acc[8][2];
  #pragma unroll
  for (int m=0;m<8;m++){ acc[m][0] = (f32x4){0,0,0,0}; acc[m][1] = (f32x4){0,0,0,0}; }
  for (int kt=0; kt<19; ++kt){
    int row = tid>>1, half = (tid&1)*16;
    const unsigned short* sp = cbf + (size_t)(mbase+row)*608 + kt*32 + half;
    *(float4*)&at[row*40 + half]     = *(const float4*)sp;
    *(float4*)&at[row*40 + half + 8] = *(const float4*)(sp + 8);
    __syncthreads();
    bf16x8 b0 = *(const bf16x8*)(cwbf + (size_t)(obase + (2*w+0)*16 + lr)*608 + kt*32 + lk);
    bf16x8 b1 = *(const bf16x8*)(cwbf + (size_t)(obase + (2*w+1)*16 + lr)*608 + kt*32 + lk);
    #pragma unroll
    for (int m=0;m<8;m++){
      bf16x8 afrag = *(const bf16x8*)&at[(m*16+lr)*40 + lk];
      acc[m][0] = __builtin_amdgcn_mfma_f32_16x16x32_bf16(afrag, b0, acc[m][0], 0,0,0);
      acc[m][1] = __builtin_amdgcn_mfma_f32_16x16x32_bf16(afrag, b1, acc[m][1], 0,0,0);
    }
    __syncthreads();
  }
  #pragma unroll
  for (int m=0;m<8;m++){
    #pragma unroll
    for (int j=0;j<2;j++){
      int o = obase + (2*w+j)*16 + lr;
      float cb = comb_b[o];
      #pragma unroll
      for (int i=0;i<4;i++){
        int r = mbase + m*16 + (l>>4)*4 + i;
        ybf[(size_t)r*1024 + o] = f2bf(ftanh(acc[m][j][i] + cb));
      }
    }
  }
}

// ---------------- out GEMM ----------------
__global__ __launch_bounds__(256) void k_out(const unsigned short* __restrict__ ybf,
    const unsigned short* __restrict__ owbf, const float* __restrict__ obias,
    float* __restrict__ obuf){
  int mbase = blockIdx.x*128;
  int tid = threadIdx.x, w = tid>>6, l = tid&63;
  int lr = l&15, lk = (l>>4)*8;
  __shared__ unsigned short at[128*40];
  f32x4 acc[8][2];
  #pragma unroll
  for (int m=0;m<8;m++){ acc[m][0] = (f32x4){0,0,0,0}; acc[m][1] = (f32x4){0,0,0,0}; }
  for (int kt=0; kt<32; ++kt){
    int row = tid>>1, half = (tid&1)*16;
    const unsigned short* sp = ybf + (size_t)(mbase+row)*1024 + kt*32 + half;
    *(float4*)&at[row*40 + half]     = *(const float4*)sp;
    *(float4*)&at[row*40 + half + 8] = *(const float4*)(sp + 8);
    __syncthreads();
    bf16x8 b0 = *(const bf16x8*)(owbf + ((2*w+0)*16 + lr)*1024 + kt*32 + lk);
    bf16x8 b1 = *(const bf16x8*)(owbf + ((2*w+1)*16 + lr)*1024 + kt*32 + lk);
    #pragma unroll
    for (int m=0;m<8;m++){
      bf16x8 afrag = *(const bf16x8*)&at[(m*16+lr)*40 + lk];
      acc[m][0] = __builtin_amdgcn_mfma_f32_16x16x32_bf16(afrag, b0, acc[m][0], 0,0,0);
      acc[m][1] = __builtin_amdgcn_mfma_f32_16x16x32_bf16(afrag, b1, acc[m][1], 0,0,0);
    }
    __syncthreads();
  }
  #pragma unroll
  for (int m=0;m<8;m++){
    #pragma unroll
    for (int j=0;j<2;j++){
      int o = (2*w+j)*16 + lr;
      float ob = obias[o];
      #pragma unroll
      for (int i=0;i<4;i++){
        int r = mbase + m*16 + (l>>4)*4 + i;
        obuf[(size_t)r*128 + o] = acc[m][j][i] + ob;
      }
    }
  }
}

// ---------------- postprocess ----------------
__global__ __launch_bounds__(256) void k_post(const float* __restrict__ obuf, float* __restrict__ out){
  int r = blockIdx.x*256 + threadIdx.x;
  if (r >= TN*TT) return;
  const float* row = obuf + (size_t)r*128;
  float mx = -1e30f;
  #pragma unroll
  for (int k2=0;k2<20;k2++) mx = fmaxf(mx, row[k2]);
  float e[20]; float s = 0;
  #pragma unroll
  for (int k2=0;k2<20;k2++){ e[k2] = __expf(row[k2]-mx); s += e[k2]; }
  float inv = __builtin_amdgcn_rcpf(s);
  float* mixo  = out;
  float* meano = out + 163840;
  float* scaleo= out + 491520;
  float* corro = out + 819200;
  float* vlogo = out + 983040;
  #pragma unroll
  for (int k2=0;k2<20;k2++) mixo[r*20+k2] = e[k2]*inv;
  #pragma unroll
  for (int j=0;j<40;j++) meano[r*40+j] = row[20+j];
  #pragma unroll
  for (int j=0;j<40;j++) scaleo[r*40+j] = __expf(row[60+j]);
  #pragma unroll
  for (int k2=0;k2<20;k2++) corro[r*20+k2] = ftanh(row[100+k2]);
  vlogo[r] = row[120];
}

extern "C" void kernel_launch(void* const* d_in, const int* in_sizes, int n_in,
                              void* d_out, int out_size, void* d_ws, size_t ws_size,
                              hipStream_t stream){
  const float* x       = (const float*)d_in[0];
  const float* x_canv  = (const float*)d_in[1];
  const float* start_  = (const float*)d_in[2];
  const float* conv1_w = (const float*)d_in[3];
  const float* conv1_b = (const float*)d_in[4];
  const float* conv2_w = (const float*)d_in[5];
  const float* conv2_b = (const float*)d_in[6];
  const float* conv3_w = (const float*)d_in[7];
  const float* conv3_b = (const float*)d_in[8];
  const float* init_w  = (const float*)d_in[9];
  const float* init_b  = (const float*)d_in[10];
  const float* Uw      = (const float*)d_in[11];
  const float* Ub      = (const float*)d_in[12];
  const float* Ww      = (const float*)d_in[13];
  const float* Wb      = (const float*)d_in[14];
  const float* vw      = (const float*)d_in[15];
  const float* vb      = (const float*)d_in[16];
  const float* beta_w  = (const float*)d_in[17];
  const float* beta_b  = (const float*)d_in[18];
  const float* xemb_w  = (const float*)d_in[19];
  const float* xemb_b  = (const float*)d_in[20];
  const float* semb_w  = (const float*)d_in[21];
  const float* semb_b  = (const float*)d_in[22];
  const float* Wih     = (const float*)d_in[23];
  const float* Whh     = (const float*)d_in[24];
  const float* bih     = (const float*)d_in[25];
  const float* bhh     = (const float*)d_in[26];
  const float* comb_w  = (const float*)d_in[27];
  const float* comb_b  = (const float*)d_in[28];
  const float* out_w   = (const float*)d_in[29];
  const float* out_b   = (const float*)d_in[30];
  (void)in_sizes; (void)n_in; (void)out_size; (void)ws_size;

  char* wsb = (char*)d_ws;
  size_t off = 0;
  auto alloc = [&](size_t bytes)->char*{
    char* p = wsb + off;
    off = (off + bytes + 255) & ~(size_t)255;
    return p;
  };
  float*          c1     = (float*)alloc((size_t)TN*16*784*4);
  unsigned short* a2     = (unsigned short*)alloc((size_t)100352*160*2);  // a3 aliases a2
  unsigned short* a3     = a2;
  unsigned short* c2bf   = (unsigned short*)alloc((size_t)100352*32*2);
  unsigned short* afbf   = (unsigned short*)alloc((size_t)TN*64*196*2);
  unsigned short* abf    = (unsigned short*)alloc((size_t)TN*196*64*2);
  float*          amean  = (float*)alloc((size_t)TN*64*4);
  float*          xe     = (float*)alloc((size_t)TN*TT*16*4);
  float*          se     = (float*)alloc((size_t)TN*16*4);
  unsigned short* wabf   = (unsigned short*)alloc((size_t)TN*196*128*2);
  float*          hbuf   = (float*)alloc((size_t)TN*512*4);
  float*          cbuf   = (float*)alloc((size_t)TN*512*4);
  unsigned short* hbf    = (unsigned short*)alloc((size_t)TN*512*2);
  unsigned short* ubf    = (unsigned short*)alloc((size_t)TN*96*2);
  unsigned short* cbf    = (unsigned short*)alloc((size_t)TN*TT*608*2);
  unsigned short* ybf    = (unsigned short*)alloc((size_t)TN*TT*1024*2);
  float*          obuf   = (float*)alloc((size_t)TN*TT*128*4);
  unsigned short* whh_bf = (unsigned short*)alloc((size_t)2048*512*2);
  unsigned short* wih_bf = (unsigned short*)alloc((size_t)2048*96*2);
  float*          gbias  = (float*)alloc((size_t)2048*4);
  unsigned short* cwbf   = (unsigned short*)alloc((size_t)1024*608*2);
  unsigned short* owbf   = (unsigned short*)alloc((size_t)128*1024*2);
  float*          obias  = (float*)alloc((size_t)128*4);
  unsigned short* uwbf   = (unsigned short*)alloc((size_t)128*512*2);
  unsigned short* betabf = (unsigned short*)alloc((size_t)64*512*2);
  unsigned short* wwbf   = (unsigned short*)alloc((size_t)128*64*2);
  unsigned short* w2b    = (unsigned short*)alloc((size_t)32*160*2);
  unsigned short* w3b    = (unsigned short*)alloc((size_t)64*320*2);
  int*            zcnt   = (int*)alloc((size_t)4096*4);
  int*            hcnt   = (int*)alloc((size_t)4096*4);

  hipLaunchKernelGGL(k_conv1, dim3(6272), dim3(256), 0, stream, x_canv, conv1_w, conv1_b, c1);
  hipLaunchKernelGGL(k_prep, dim3(8333), dim3(256), 0, stream,
                     Whh, Wih, bih, bhh, comb_w, out_w, out_b, Uw, beta_w, Ww, conv2_w, conv3_w,
                     whh_bf, wih_bf, gbias, cwbf, owbf, obias, uwbf, betabf, wwbf, w2b, w3b);
  hipLaunchKernelGGL(k_im2col2, dim3(62720), dim3(256), 0, stream, c1, a2);
  hipLaunchKernelGGL(k_gconv2, dim3(784), dim3(256), 0, stream, a2, w2b, conv2_b, c2bf);
  hipLaunchKernelGGL(k_im2col3, dim3(31360), dim3(256), 0, stream, c2bf, a3);
  hipLaunchKernelGGL(k_gconv3, dim3(196), dim3(256), 0, stream, a3, w3b, conv3_b, afbf, abf);
  hipLaunchKernelGGL(k_amean, dim3(128), dim3(64), 0, stream, afbf, amean);
  hipLaunchKernelGGL(k_embed, dim3(520), dim3(256), 0, stream, x, start_, xemb_w, xemb_b, semb_w, semb_b, xe, se);
  hipLaunchKernelGGL(k_init, dim3(544), dim3(256), 0, stream, amean, se, init_w, init_b, hbuf, cbuf, hbf, zcnt, hcnt);
  hipLaunchKernelGGL(k_wa, dim3(196), dim3(256), 0, stream, abf, wwbf, Wb, wabf);
  hipLaunchKernelGGL(k_cbf_xs, dim3(1024), dim3(256), 0, stream, xe, se, cbf);

  hipLaunchKernelGGL(k_loop, dim3(NB), dim3(512), 0, stream,
                     uwbf, Ub, betabf, beta_b, vw, vb, wabf, afbf, xe,
                     whh_bf, wih_bf, gbias,
                     hbuf, cbuf, hbf, ubf, cbf, zcnt, hcnt);

  hipLaunchKernelGGL(k_comb, dim3(64, 8), dim3(256), 0, stream, cbf, cwbf, comb_b, ybf);
  hipLaunchKernelGGL(k_out, dim3(64), dim3(256), 0, stream, ybf, owbf, obias, obuf);
  hipLaunchKernelGGL(k_post, dim3(32), dim3(256), 0, stream, obuf, (float*)d_out);
}

// Round 7
// 11486.488 us; speedup vs baseline: 1.0307x; 1.0307x over previous
//
#include <hip/hip_runtime.h>

// LSTMConditioned: conv-encoder + attention-LSTM (T=64) + MDN head.
// N=128, T=64, HID=512, COMB=1024, ATT=128, K=20, D=2, FMAP=64, L=196, ODIM=121.
// Recurrence: ONE persistent kernel, 32 blocks x 512 threads, each block owns 4 samples
// end-to-end. ZERO cross-block sync (weights shared read-only via L2).
// Waves 0-3: gates GEMM (MFMA, weights streamed from L2, c-state in VGPRs).
// Waves 4-7: attention (one sample each): Uh/beta MFMA, tanh e-phase, in-wave softmax, z.

#define TN 128
#define TT 64

typedef __attribute__((ext_vector_type(4))) float f32x4;
typedef __attribute__((ext_vector_type(8))) short bf16x8;

__device__ __forceinline__ float fsigm(float x){ return __builtin_amdgcn_rcpf(1.0f + __expf(-x)); }
__device__ __forceinline__ float ftanh(float x){ return 1.0f - 2.0f*__builtin_amdgcn_rcpf(1.0f + __expf(2.0f*x)); }
__device__ __forceinline__ unsigned short f2bf(float f){
  unsigned int u = __float_as_uint(f);
  u += 0x7fffu + ((u >> 16) & 1u);
  return (unsigned short)(u >> 16);
}
__device__ __forceinline__ float b2f(unsigned short u){ return __uint_as_float(((unsigned)u)<<16); }

// ---------------- conv1 (direct, small) ----------------
__global__ __launch_bounds__(256) void k_conv1(const float* __restrict__ xc, const float* __restrict__ w,
                                               const float* __restrict__ b, float* __restrict__ c1){
  int idx = blockIdx.x*256 + threadIdx.x;
  if (idx >= TN*16*784) return;
  int p = idx % 784, oc = (idx/784) & 15, n = idx/(784*16);
  int py = p/28, px = p%28;
  const float* src = xc + n*784;
  float acc = b[oc];
  #pragma unroll
  for (int ky=0;ky<3;ky++){
    int iy = py+ky-1; if (iy<0||iy>=28) continue;
    #pragma unroll
    for (int kx=0;kx<3;kx++){
      int ix = px+kx-1; if (ix<0||ix>=28) continue;
      acc += (src[iy*28+ix]-0.0243f)*(1.0f/0.1383f) * w[oc*9+ky*3+kx];
    }
  }
  c1[idx] = fmaxf(acc, 0.0f);
}

// ---------------- im2col for conv2 ----------------
__global__ __launch_bounds__(256) void k_im2col2(const float* __restrict__ c1, unsigned short* __restrict__ a2){
  int idx = blockIdx.x*256 + threadIdx.x;   // 62720*256 = 100352*160
  int k = idx % 160, r = idx / 160;
  unsigned short v = 0;
  if (k < 144){
    int ic = k/9, rem = k - ic*9, ky = rem/3, kx = rem - ky*3;
    int p = r % 784, n = r / 784;
    int py = p/28, px = p%28;
    int iy = py+ky-1, ix = px+kx-1;
    if (iy>=0 && iy<28 && ix>=0 && ix<28) v = f2bf(c1[(n*16+ic)*784 + iy*28+ix]);
  }
  a2[idx] = v;
}

// ---------------- conv2 GEMM ----------------
__global__ __launch_bounds__(256) void k_gconv2(const unsigned short* __restrict__ a2,
    const unsigned short* __restrict__ w2b, const float* __restrict__ b2,
    unsigned short* __restrict__ c2bf){
  int mbase = blockIdx.x*128;           // 784 blocks
  int tid = threadIdx.x, w = tid>>6, l = tid&63;
  int lr = l&15, lk = (l>>4)*8;
  __shared__ unsigned short at[128*168];
  {
    int row = tid>>1, off = (tid&1)*80;
    const unsigned short* sp = a2 + (size_t)(mbase+row)*160 + off;
    #pragma unroll
    for (int j=0;j<10;j++) *(float4*)&at[row*168 + off + j*8] = *(const float4*)(sp + j*8);
  }
  __syncthreads();
  f32x4 acc[2][2];
  #pragma unroll
  for (int mi=0;mi<2;mi++){ acc[mi][0]=(f32x4){0,0,0,0}; acc[mi][1]=(f32x4){0,0,0,0}; }
  for (int kt=0; kt<5; ++kt){
    bf16x8 b0 = *(const bf16x8*)(w2b + (0*16+lr)*160 + kt*32 + lk);
    bf16x8 b1 = *(const bf16x8*)(w2b + (1*16+lr)*160 + kt*32 + lk);
    #pragma unroll
    for (int mi=0;mi<2;mi++){
      bf16x8 afrag = *(const bf16x8*)&at[((2*w+mi)*16+lr)*168 + kt*32 + lk];
      acc[mi][0] = __builtin_amdgcn_mfma_f32_16x16x32_bf16(afrag, b0, acc[mi][0], 0,0,0);
      acc[mi][1] = __builtin_amdgcn_mfma_f32_16x16x32_bf16(afrag, b1, acc[mi][1], 0,0,0);
    }
  }
  #pragma unroll
  for (int mi=0;mi<2;mi++){
    #pragma unroll
    for (int j=0;j<2;j++){
      int oc = j*16 + lr;
      float bb = b2[oc];
      #pragma unroll
      for (int i=0;i<4;i++){
        int r = mbase + (2*w+mi)*16 + (l>>4)*4 + i;
        c2bf[(size_t)r*32 + oc] = f2bf(fmaxf(acc[mi][j][i] + bb, 0.0f));
      }
    }
  }
}

// ---------------- im2col for conv3 (stride 2) ----------------
__global__ __launch_bounds__(256) void k_im2col3(const unsigned short* __restrict__ c2bf, unsigned short* __restrict__ a3){
  int idx = blockIdx.x*256 + threadIdx.x;   // 31360*256 = 25088*320
  int k = idx % 320, r = idx / 320;
  unsigned short v = 0;
  if (k < 288){
    int ic = k/9, rem = k - ic*9, ky = rem/3, kx = rem - ky*3;
    int p = r % 196, n = r / 196;
    int py = p/14, px = p%14;
    int iy = 2*py+ky-1, ix = 2*px+kx-1;
    if (iy>=0 && iy<28 && ix>=0 && ix<28) v = c2bf[(size_t)(n*784 + iy*28+ix)*32 + ic];
  }
  a3[idx] = v;
}

// ---------------- conv3 GEMM: afbf[n][f][l] (bf16) + abf[r][f] (bf16) ----------------
__global__ __launch_bounds__(256) void k_gconv3(const unsigned short* __restrict__ a3,
    const unsigned short* __restrict__ w3b, const float* __restrict__ b3,
    unsigned short* __restrict__ afbf, unsigned short* __restrict__ abf){
  int mbase = blockIdx.x*128;           // 196 blocks
  int tid = threadIdx.x, w = tid>>6, l = tid&63;
  int lr = l&15, lk = (l>>4)*8;
  __shared__ unsigned short at[128*168];
  f32x4 acc[2][4];
  #pragma unroll
  for (int mi=0;mi<2;mi++)
    #pragma unroll
    for (int j=0;j<4;j++) acc[mi][j]=(f32x4){0,0,0,0};
  for (int kt2=0; kt2<2; ++kt2){
    {
      int row = tid>>1, off = (tid&1)*80;
      const unsigned short* sp = a3 + (size_t)(mbase+row)*320 + kt2*160 + off;
      #pragma unroll
      for (int j=0;j<10;j++) *(float4*)&at[row*168 + off + j*8] = *(const float4*)(sp + j*8);
    }
    __syncthreads();
    for (int kt=0; kt<5; ++kt){
      #pragma unroll
      for (int mi=0;mi<2;mi++){
        bf16x8 afrag = *(const bf16x8*)&at[((2*w+mi)*16+lr)*168 + kt*32 + lk];
        #pragma unroll
        for (int j=0;j<4;j++){
          bf16x8 bf = *(const bf16x8*)(w3b + (size_t)(j*16+lr)*320 + kt2*160 + kt*32 + lk);
          acc[mi][j] = __builtin_amdgcn_mfma_f32_16x16x32_bf16(afrag, bf, acc[mi][j], 0,0,0);
        }
      }
    }
    __syncthreads();
  }
  #pragma unroll
  for (int mi=0;mi<2;mi++){
    #pragma unroll
    for (int j=0;j<4;j++){
      int oc = j*16 + lr;
      float bb = b3[oc];
      #pragma unroll
      for (int i=0;i<4;i++){
        int r = mbase + (2*w+mi)*16 + (l>>4)*4 + i;
        int n = r/196, p = r - n*196;
        float v = ftanh(acc[mi][j][i] + bb);
        unsigned short vb16 = f2bf(v);
        afbf[(size_t)(n*64+oc)*196 + p] = vb16;
        abf[(size_t)r*64 + oc] = vb16;
      }
    }
  }
}

__global__ __launch_bounds__(64) void k_amean(const unsigned short* __restrict__ afbf, float* __restrict__ amean){
  int n = blockIdx.x, f = threadIdx.x;
  const unsigned short* row = afbf + (size_t)(n*64+f)*196;
  float s = 0;
  for (int l=0;l<196;l++) s += b2f(row[l]);
  amean[n*64+f] = s * (1.0f/196.0f);
}

// ---------------- embeddings / init ----------------
__global__ __launch_bounds__(256) void k_embed(const float* __restrict__ x, const float* __restrict__ start,
    const float* __restrict__ xw, const float* __restrict__ xb,
    const float* __restrict__ sw, const float* __restrict__ sb,
    float* __restrict__ xe, float* __restrict__ se){
  int idx = blockIdx.x*256 + threadIdx.x;
  if (idx < TN*TT*16){
    int j = idx & 15, t = (idx>>4) & 63, n = idx>>10;
    float acc = xb[j];
    if (t > 0){
      const float* xp = x + (n*TT + t-1)*2;
      acc += xp[0]*xw[j*2] + xp[1]*xw[j*2+1];
    }
    xe[idx] = ftanh(acc);
  } else if (idx < TN*TT*16 + TN*16){
    int k2 = idx - TN*TT*16;
    int j = k2 & 15, n = k2 >> 4;
    float acc = sb[j] + start[n*2]*sw[j*2] + start[n*2+1]*sw[j*2+1];
    se[k2] = ftanh(acc);
  }
}

__global__ __launch_bounds__(256) void k_init(const float* __restrict__ amean, const float* __restrict__ se,
    const float* __restrict__ w, const float* __restrict__ b,
    float* __restrict__ hbuf, float* __restrict__ cbuf){
  int idx = blockIdx.x*256 + threadIdx.x;
  if (idx >= TN*1024) return;
  int o = idx & 1023, n = idx >> 10;
  const float* wr = w + o*80;
  float acc = b[o];
  for (int k2=0;k2<64;k2++) acc += amean[n*64+k2]*wr[k2];
  for (int k2=0;k2<16;k2++) acc += se[n*16+k2]*wr[64+k2];
  float v = ftanh(acc);
  if (o & 1) cbuf[n*512 + (o>>1)] = v;
  else       hbuf[n*512 + (o>>1)] = v;
}

// ---------------- weight prep ----------------
__global__ __launch_bounds__(256) void k_prep(
    const float* __restrict__ Whh, const float* __restrict__ Wih,
    const float* __restrict__ bih, const float* __restrict__ bhh,
    const float* __restrict__ comb_w, const float* __restrict__ out_w, const float* __restrict__ out_b,
    const float* __restrict__ Uw, const float* __restrict__ beta_w, const float* __restrict__ Ww,
    const float* __restrict__ conv2_w, const float* __restrict__ conv3_w,
    unsigned short* __restrict__ whh_bf, unsigned short* __restrict__ wih_bf, float* __restrict__ gbias,
    unsigned short* __restrict__ cwbf, unsigned short* __restrict__ owbf, float* __restrict__ obias,
    unsigned short* __restrict__ uwbf, unsigned short* __restrict__ betabf, unsigned short* __restrict__ wwbf,
    unsigned short* __restrict__ w2b, unsigned short* __restrict__ w3b){
  int idx = blockIdx.x*256 + threadIdx.x;
  if (idx < 1048576){ whh_bf[idx] = f2bf(Whh[idx]); return; }
  idx -= 1048576;
  if (idx < 196608){ int o = idx/96, k2 = idx%96; wih_bf[idx] = (k2<80) ? f2bf(Wih[o*80+k2]) : (unsigned short)0; return; }
  idx -= 196608;
  if (idx < 2048){ gbias[idx] = bih[idx]+bhh[idx]; return; }
  idx -= 2048;
  if (idx < 622592){ cwbf[idx] = f2bf(comb_w[idx]); return; }
  idx -= 622592;
  if (idx < 131072){ int o = idx>>10, k2 = idx & 1023; owbf[idx] = (o<121)? f2bf(out_w[o*1024+k2]) : (unsigned short)0; return; }
  idx -= 131072;
  if (idx < 128){ obias[idx] = (idx<121)? out_b[idx] : 0.0f; return; }
  idx -= 128;
  if (idx < 65536){ uwbf[idx] = f2bf(Uw[idx]); return; }
  idx -= 65536;
  if (idx < 32768){ betabf[idx] = f2bf(beta_w[idx]); return; }
  idx -= 32768;
  if (idx < 8192){ wwbf[idx] = f2bf(Ww[idx]); return; }
  idx -= 8192;
  if (idx < 5120){ int o = idx/160, k2 = idx - o*160; w2b[idx] = (k2<144)? f2bf(conv2_w[o*144+k2]) : (unsigned short)0; return; }
  idx -= 5120;
  if (idx < 20480){ int o = idx/320, k2 = idx - o*320; w3b[idx] = (k2<288)? f2bf(conv3_w[o*288+k2]) : (unsigned short)0; return; }
}

// ---------------- W_a = a @ Ww.T + Wb (MFMA), stored bf16 [n][l][att] ----------------
__global__ __launch_bounds__(256) void k_wa(const unsigned short* __restrict__ abf,
    const unsigned short* __restrict__ wwbf, const float* __restrict__ Wb,
    unsigned short* __restrict__ wabf){
  int mbase = blockIdx.x*128;
  int tid = threadIdx.x, w = tid>>6, l = tid&63;
  int lr = l & 15, lk = (l>>4)*8;
  __shared__ unsigned short at[128*40];
  f32x4 acc[8][2];
  #pragma unroll
  for (int m=0;m<8;m++){ acc[m][0] = (f32x4){0,0,0,0}; acc[m][1] = (f32x4){0,0,0,0}; }
  for (int kt=0; kt<2; ++kt){
    int row = tid>>1, half = (tid&1)*16;
    const unsigned short* sp = abf + (mbase+row)*64 + kt*32 + half;
    *(float4*)&at[row*40 + half]     = *(const float4*)sp;
    *(float4*)&at[row*40 + half + 8] = *(const float4*)(sp + 8);
    __syncthreads();
    bf16x8 b0 = *(const bf16x8*)(wwbf + ((2*w+0)*16 + lr)*64 + kt*32 + lk);
    bf16x8 b1 = *(const bf16x8*)(wwbf + ((2*w+1)*16 + lr)*64 + kt*32 + lk);
    #pragma unroll
    for (int m=0;m<8;m++){
      bf16x8 afrag = *(const bf16x8*)&at[(m*16+lr)*40 + lk];
      acc[m][0] = __builtin_amdgcn_mfma_f32_16x16x32_bf16(afrag, b0, acc[m][0], 0,0,0);
      acc[m][1] = __builtin_amdgcn_mfma_f32_16x16x32_bf16(afrag, b1, acc[m][1], 0,0,0);
    }
    __syncthreads();
  }
  #pragma unroll
  for (int m=0;m<8;m++){
    #pragma unroll
    for (int j=0;j<2;j++){
      int att = (2*w+j)*16 + lr;
      float wb = Wb[att];
      #pragma unroll
      for (int i=0;i<4;i++){
        int arow = mbase + m*16 + (l>>4)*4 + i;
        int n = arow/196, l2 = arow - n*196;
        wabf[((size_t)n*196 + l2)*128 + att] = f2bf(acc[m][j][i] + wb);
      }
    }
  }
}

// ---------------- persistent recurrence: 32 blocks x 4 samples, zero cross-block sync ----------------
__global__ __launch_bounds__(512) void k_loop(
    const unsigned short* __restrict__ uwbf, const float* __restrict__ Ub,
    const unsigned short* __restrict__ betabf, const float* __restrict__ beta_b,
    const float* __restrict__ vw, const float* __restrict__ vb,
    const unsigned short* __restrict__ wabf, const unsigned short* __restrict__ afbf,
    const float* __restrict__ xe,
    const unsigned short* __restrict__ whh_bf, const unsigned short* __restrict__ wih_bf,
    const float* __restrict__ gbias,
    const float* __restrict__ hbuf, const float* __restrict__ cbuf,
    unsigned short* __restrict__ cbf)
{
  const int bid = blockIdx.x, tid = threadIdx.x;
  const int w = tid>>6, l = tid&63, lr = l&15, li = l>>4, lk = li*8;
  const int nb = bid*4;
  __shared__ __align__(16) unsigned short at[16*616];  // A-tile: rows 0-3 samples; cols 0-511 h, 512-527 xe, 528-591 z, 592-607 zero
  __shared__ float uh[4*132];
  __shared__ float bsg[4*64];
  __shared__ float alp[4*208];
  __shared__ float vwl[128];

  for (int i = tid; i < 16*616; i += 512) at[i] = 0;
  if (tid < 128) vwl[tid] = vw[tid];
  const float vb0 = vb[0];
  __syncthreads();
  for (int i = tid; i < 2048; i += 512){
    int r = i>>9, c = i&511;
    at[r*616 + c] = f2bf(hbuf[(nb+r)*512 + c]);
  }
  float cr[8][4];
  if (w < 4 && li == 0){
    #pragma unroll
    for (int jt=0;jt<8;jt++)
      #pragma unroll
      for (int i=0;i<4;i++)
        cr[jt][i] = cbuf[(nb+i)*512 + w*128 + jt*16 + lr];
  }
  __syncthreads();

  for (int t = 0; t < TT; ++t){
    // ---- phase 0: attention waves compute Uh / beta via MFMA (gates waves pass through) ----
    if (w >= 4){
      int j = w-4;
      #pragma unroll
      for (int tt=0; tt<3; ++tt){
        int tile = j*3+tt;
        const unsigned short* bw = (tile<8) ? (uwbf + (size_t)(tile*16+lr)*512 + lk)
                                            : (betabf + (size_t)((tile-8)*16+lr)*512 + lk);
        f32x4 acc1 = (f32x4){0,0,0,0};
        #pragma unroll
        for (int kt=0;kt<16;++kt){
          bf16x8 a = *(const bf16x8*)&at[lr*616 + kt*32 + lk];
          bf16x8 b = *(const bf16x8*)(bw + kt*32);
          acc1 = __builtin_amdgcn_mfma_f32_16x16x32_bf16(a,b,acc1,0,0,0);
        }
        if (li==0){
          if (tile<8){
            float ub = Ub[tile*16+lr];
            #pragma unroll
            for (int i=0;i<4;i++) uh[i*132 + tile*16 + lr] = acc1[i] + ub;
          } else {
            float bb = beta_b[(tile-8)*16+lr];
            #pragma unroll
            for (int i=0;i<4;i++) bsg[i*64 + (tile-8)*16 + lr] = fsigm(acc1[i] + bb);
          }
        }
      }
    }
    __syncthreads();   // sync1: uh/bsg ready
    f32x4 acc[4][8];
    if (w < 4){
      // ---- gates h-part: 32 tiles (4 gates x 8 hidx-tiles), kt 0..15 ----
      #pragma unroll
      for (int g=0;g<4;g++)
        #pragma unroll
        for (int jt=0;jt<8;jt++)
          acc[g][jt] = (f32x4){0,0,0,0};
      for (int kt=0;kt<16;++kt){
        bf16x8 a = *(const bf16x8*)&at[lr*616 + kt*32 + lk];
        #pragma unroll
        for (int g=0;g<4;g++)
          #pragma unroll
          for (int jt=0;jt<8;jt++){
            bf16x8 b = *(const bf16x8*)(whh_bf + (size_t)(g*512 + w*128 + jt*16 + lr)*512 + kt*32 + lk);
            acc[g][jt] = __builtin_amdgcn_mfma_f32_16x16x32_bf16(a,b,acc[g][jt],0,0,0);
          }
      }
    } else {
      // ---- attention wave: sample s = w-4 ----
      const int s = w-4, n = nb+s;
      float ev[4];
      #pragma unroll
      for (int rep=0;rep<4;++rep){
        int ll = l + rep*64;
        float a = -1e30f;
        if (ll < 196){
          const unsigned short* wr = wabf + ((size_t)n*196 + ll)*128;
          a = vb0;
          for (int k=0;k<128;k+=8){
            bf16x8 wv = *(const bf16x8*)(wr + k);
            #pragma unroll
            for (int m=0;m<8;m++)
              a += vwl[k+m]*ftanh(b2f((unsigned short)wv[m]) + uh[s*132 + k+m]);
          }
        }
        ev[rep] = a;
      }
      float mx = fmaxf(fmaxf(ev[0],ev[1]),fmaxf(ev[2],ev[3]));
      #pragma unroll
      for (int off=32; off>0; off>>=1) mx = fmaxf(mx, __shfl_xor(mx, off));
      float er[4], sum=0.f;
      #pragma unroll
      for (int rep=0;rep<4;++rep){
        int ll = l + rep*64;
        er[rep] = (ll<196)? __expf(ev[rep]-mx) : 0.f;
        sum += er[rep];
      }
      #pragma unroll
      for (int off=32; off>0; off>>=1) sum += __shfl_xor(sum, off);
      float inv = __builtin_amdgcn_rcpf(sum);
      #pragma unroll
      for (int rep=0;rep<4;++rep){
        int ll = l + rep*64;
        if (ll<196) alp[s*208+ll] = er[rep]*inv;
      }
      asm volatile("s_waitcnt lgkmcnt(0)" ::: "memory");  // in-wave LDS write->read ordering
      // z[f=l] = bsig * sum_l alpha*a
      float zacc = 0.f;
      const unsigned short* an = afbf + (size_t)n*12544 + (size_t)l*196;
      for (int l2=0;l2<196;l2++) zacc += alp[s*208+l2]*b2f(an[l2]);
      float z = bsg[s*64+l]*zacc;
      unsigned short zb = f2bf(z);
      at[s*616 + 528 + l] = zb;
      cbf[((size_t)n*TT+t)*608 + 512 + l] = zb;
      if (l < 16) at[s*616 + 512 + l] = f2bf(xe[((size_t)n*TT + t)*16 + l]);
    }
    __syncthreads();  // sync2: z/xe cols ready
    if (w < 4){
      // ---- gates z-part: kt 16..18 ----
      #pragma unroll
      for (int kt=16;kt<19;++kt){
        bf16x8 a = *(const bf16x8*)&at[lr*616 + kt*32 + lk];
        #pragma unroll
        for (int g=0;g<4;g++)
          #pragma unroll
          for (int jt=0;jt<8;jt++){
            bf16x8 b = *(const bf16x8*)(wih_bf + (size_t)(g*512 + w*128 + jt*16 + lr)*96 + (kt-16)*32 + lk);
            acc[g][jt] = __builtin_amdgcn_mfma_f32_16x16x32_bf16(a,b,acc[g][jt],0,0,0);
          }
      }
    }
    __syncthreads();  // sync3: all at-reads drained before h overwrite
    if (w < 4 && li == 0){
      // ---- cell update: lanes 0-15 hold samples 0-3 in acc rows ----
      #pragma unroll
      for (int jt=0;jt<8;jt++){
        int hx = w*128 + jt*16 + lr;
        float b0 = gbias[hx], b1 = gbias[512+hx], b2v = gbias[1024+hx], b3v = gbias[1536+hx];
        #pragma unroll
        for (int i=0;i<4;i++){
          float gi = acc[0][jt][i] + b0;
          float gf = acc[1][jt][i] + b1;
          float gg = acc[2][jt][i] + b2v;
          float go = acc[3][jt][i] + b3v;
          float cs = fsigm(gf)*cr[jt][i] + fsigm(gi)*ftanh(gg);
          float h  = fsigm(go)*ftanh(cs);
          cr[jt][i] = cs;
          unsigned short hb = f2bf(h);
          at[i*616 + hx] = hb;
          cbf[((size_t)(nb+i)*TT+t)*608 + hx] = hb;
        }
      }
    }
    __syncthreads();  // sync4: h ready for next step
  }
}

// ---------------- comb-input xe/se slices ----------------
__global__ __launch_bounds__(256) void k_cbf_xs(const float* __restrict__ xe, const float* __restrict__ se,
                                                unsigned short* __restrict__ cbf){
  int idx = blockIdx.x*256 + threadIdx.x;
  if (idx >= TN*TT*32) return;
  int j = idx & 31, r = idx >> 5;
  int n = r >> 6;
  if (j < 16) cbf[(size_t)r*608 + 576 + j] = f2bf(xe[r*16 + j]);
  else        cbf[(size_t)r*608 + 592 + (j-16)] = f2bf(se[n*16 + (j-16)]);
}

// ---------------- comb GEMM ----------------
__global__ __launch_bounds__(256) void k_comb(const unsigned short* __restrict__ cbf,
    const unsigned short* __restrict__ cwbf, const float* __restrict__ comb_b,
    unsigned short* __restrict__ ybf){
  int mbase = blockIdx.x*128, obase = blockIdx.y*128;
  int tid = threadIdx.x, w = tid>>6, l = tid&63;
  int lr = l&15, lk = (l>>4)*8;
  __shared__ unsigned short at[128*40];
  f32x4 acc[8][2];
  #pragma unroll
  for (int m=0;m<8;m++){ acc[m][0] = (f32x4){0,0,0,0}; acc[m][1] = (f32x4){0,0,0,0}; }
  for (int kt=0; kt<19; ++kt){
    int row = tid>>1, half = (tid&1)*16;
    const unsigned short* sp = cbf + (size_t)(mbase+row)*608 + kt*32 + half;
    *(float4*)&at[row*40 + half]     = *(const float4*)sp;
    *(float4*)&at[row*40 + half + 8] = *(const float4*)(sp + 8);
    __syncthreads();
    bf16x8 b0 = *(const bf16x8*)(cwbf + (size_t)(obase + (2*w+0)*16 + lr)*608 + kt*32 + lk);
    bf16x8 b1 = *(const bf16x8*)(cwbf + (size_t)(obase + (2*w+1)*16 + lr)*608 + kt*32 + lk);
    #pragma unroll
    for (int m=0;m<8;m++){
      bf16x8 afrag = *(const bf16x8*)&at[(m*16+lr)*40 + lk];
      acc[m][0] = __builtin_amdgcn_mfma_f32_16x16x32_bf16(afrag, b0, acc[m][0], 0,0,0);
      acc[m][1] = __builtin_amdgcn_mfma_f32_16x16x32_bf16(afrag, b1, acc[m][1], 0,0,0);
    }
    __syncthreads();
  }
  #pragma unroll
  for (int m=0;m<8;m++){
    #pragma unroll
    for (int j=0;j<2;j++){
      int o = obase + (2*w+j)*16 + lr;
      float cb = comb_b[o];
      #pragma unroll
      for (int i=0;i<4;i++){
        int r = mbase + m*16 + (l>>4)*4 + i;
        ybf[(size_t)r*1024 + o] = f2bf(ftanh(acc[m][j][i] + cb));
      }
    }
  }
}

// ---------------- out GEMM ----------------
__global__ __launch_bounds__(256) void k_out(const unsigned short* __restrict__ ybf,
    const unsigned short* __restrict__ owbf, const float* __restrict__ obias,
    float* __restrict__ obuf){
  int mbase = blockIdx.x*128;
  int tid = threadIdx.x, w = tid>>6, l = tid&63;
  int lr = l&15, lk = (l>>4)*8;
  __shared__ unsigned short at[128*40];
  f32x4 acc[8][2];
  #pragma unroll
  for (int m=0;m<8;m++){ acc[m][0] = (f32x4){0,0,0,0}; acc[m][1] = (f32x4){0,0,0,0}; }
  for (int kt=0; kt<32; ++kt){
    int row = tid>>1, half = (tid&1)*16;
    const unsigned short* sp = ybf + (size_t)(mbase+row)*1024 + kt*32 + half;
    *(float4*)&at[row*40 + half]     = *(const float4*)sp;
    *(float4*)&at[row*40 + half + 8] = *(const float4*)(sp + 8);
    __syncthreads();
    bf16x8 b0 = *(const bf16x8*)(owbf + ((2*w+0)*16 + lr)*1024 + kt*32 + lk);
    bf16x8 b1 = *(const bf16x8*)(owbf + ((2*w+1)*16 + lr)*1024 + kt*32 + lk);
    #pragma unroll
    for (int m=0;m<8;m++){
      bf16x8 afrag = *(const bf16x8*)&at[(m*16+lr)*40 + lk];
      acc[m][0] = __builtin_amdgcn_mfma_f32_16x16x32_bf16(afrag, b0, acc[m][0], 0,0,0);
      acc[m][1] = __builtin_amdgcn_mfma_f32_16x16x32_bf16(afrag, b1, acc[m][1], 0,0,0);
    }
    __syncthreads();
  }
  #pragma unroll
  for (int m=0;m<8;m++){
    #pragma unroll
    for (int j=0;j<2;j++){
      int o = (2*w+j)*16 + lr;
      float ob = obias[o];
      #pragma unroll
      for (int i=0;i<4;i++){
        int r = mbase + m*16 + (l>>4)*4 + i;
        obuf[(size_t)r*128 + o] = acc[m][j][i] + ob;
      }
    }
  }
}

// ---------------- postprocess ----------------
__global__ __launch_bounds__(256) void k_post(const float* __restrict__ obuf, float* __restrict__ out){
  int r = blockIdx.x*256 + threadIdx.x;
  if (r >= TN*TT) return;
  const float* row = obuf + (size_t)r*128;
  float mx = -1e30f;
  #pragma unroll
  for (int k2=0;k2<20;k2++) mx = fmaxf(mx, row[k2]);
  float e[20]; float s = 0;
  #pragma unroll
  for (int k2=0;k2<20;k2++){ e[k2] = __expf(row[k2]-mx); s += e[k2]; }
  float inv = __builtin_amdgcn_rcpf(s);
  float* mixo  = out;
  float* meano = out + 163840;
  float* scaleo= out + 491520;
  float* corro = out + 819200;
  float* vlogo = out + 983040;
  #pragma unroll
  for (int k2=0;k2<20;k2++) mixo[r*20+k2] = e[k2]*inv;
  #pragma unroll
  for (int j=0;j<40;j++) meano[r*40+j] = row[20+j];
  #pragma unroll
  for (int j=0;j<40;j++) scaleo[r*40+j] = __expf(row[60+j]);
  #pragma unroll
  for (int k2=0;k2<20;k2++) corro[r*20+k2] = ftanh(row[100+k2]);
  vlogo[r] = row[120];
}

extern "C" void kernel_launch(void* const* d_in, const int* in_sizes, int n_in,
                              void* d_out, int out_size, void* d_ws, size_t ws_size,
                              hipStream_t stream){
  const float* x       = (const float*)d_in[0];
  const float* x_canv  = (const float*)d_in[1];
  const float* start_  = (const float*)d_in[2];
  const float* conv1_w = (const float*)d_in[3];
  const float* conv1_b = (const float*)d_in[4];
  const float* conv2_w = (const float*)d_in[5];
  const float* conv2_b = (const float*)d_in[6];
  const float* conv3_w = (const float*)d_in[7];
  const float* conv3_b = (const float*)d_in[8];
  const float* init_w  = (const float*)d_in[9];
  const float* init_b  = (const float*)d_in[10];
  const float* Uw      = (const float*)d_in[11];
  const float* Ub      = (const float*)d_in[12];
  const float* Ww      = (const float*)d_in[13];
  const float* Wb      = (const float*)d_in[14];
  const float* vw      = (const float*)d_in[15];
  const float* vb      = (const float*)d_in[16];
  const float* beta_w  = (const float*)d_in[17];
  const float* beta_b  = (const float*)d_in[18];
  const float* xemb_w  = (const float*)d_in[19];
  const float* xemb_b  = (const float*)d_in[20];
  const float* semb_w  = (const float*)d_in[21];
  const float* semb_b  = (const float*)d_in[22];
  const float* Wih     = (const float*)d_in[23];
  const float* Whh     = (const float*)d_in[24];
  const float* bih     = (const float*)d_in[25];
  const float* bhh     = (const float*)d_in[26];
  const float* comb_w  = (const float*)d_in[27];
  const float* comb_b  = (const float*)d_in[28];
  const float* out_w   = (const float*)d_in[29];
  const float* out_b   = (const float*)d_in[30];
  (void)in_sizes; (void)n_in; (void)out_size; (void)ws_size;

  char* wsb = (char*)d_ws;
  size_t off = 0;
  auto alloc = [&](size_t bytes)->char*{
    char* p = wsb + off;
    off = (off + bytes + 255) & ~(size_t)255;
    return p;
  };
  float*          c1     = (float*)alloc((size_t)TN*16*784*4);
  unsigned short* a2     = (unsigned short*)alloc((size_t)100352*160*2);  // a3 aliases a2
  unsigned short* a3     = a2;
  unsigned short* c2bf   = (unsigned short*)alloc((size_t)100352*32*2);
  unsigned short* afbf   = (unsigned short*)alloc((size_t)TN*64*196*2);
  unsigned short* abf    = (unsigned short*)alloc((size_t)TN*196*64*2);
  float*          amean  = (float*)alloc((size_t)TN*64*4);
  float*          xe     = (float*)alloc((size_t)TN*TT*16*4);
  float*          se     = (float*)alloc((size_t)TN*16*4);
  unsigned short* wabf   = (unsigned short*)alloc((size_t)TN*196*128*2);
  float*          hbuf   = (float*)alloc((size_t)TN*512*4);
  float*          cbuf   = (float*)alloc((size_t)TN*512*4);
  unsigned short* cbf    = (unsigned short*)alloc((size_t)TN*TT*608*2);
  unsigned short* ybf    = (unsigned short*)alloc((size_t)TN*TT*1024*2);
  float*          obuf   = (float*)alloc((size_t)TN*TT*128*4);
  unsigned short* whh_bf = (unsigned short*)alloc((size_t)2048*512*2);
  unsigned short* wih_bf = (unsigned short*)alloc((size_t)2048*96*2);
  float*          gbias  = (float*)alloc((size_t)2048*4);
  unsigned short* cwbf   = (unsigned short*)alloc((size_t)1024*608*2);
  unsigned short* owbf   = (unsigned short*)alloc((size_t)128*1024*2);
  float*          obias  = (float*)alloc((size_t)128*4);
  unsigned short* uwbf   = (unsigned short*)alloc((size_t)128*512*2);
  unsigned short* betabf = (unsigned short*)alloc((size_t)64*512*2);
  unsigned short* wwbf   = (unsigned short*)alloc((size_t)128*64*2);
  unsigned short* w2b    = (unsigned short*)alloc((size_t)32*160*2);
  unsigned short* w3b    = (unsigned short*)alloc((size_t)64*320*2);

  hipLaunchKernelGGL(k_conv1, dim3(6272), dim3(256), 0, stream, x_canv, conv1_w, conv1_b, c1);
  hipLaunchKernelGGL(k_prep, dim3(8333), dim3(256), 0, stream,
                     Whh, Wih, bih, bhh, comb_w, out_w, out_b, Uw, beta_w, Ww, conv2_w, conv3_w,
                     whh_bf, wih_bf, gbias, cwbf, owbf, obias, uwbf, betabf, wwbf, w2b, w3b);
  hipLaunchKernelGGL(k_im2col2, dim3(62720), dim3(256), 0, stream, c1, a2);
  hipLaunchKernelGGL(k_gconv2, dim3(784), dim3(256), 0, stream, a2, w2b, conv2_b, c2bf);
  hipLaunchKernelGGL(k_im2col3, dim3(31360), dim3(256), 0, stream, c2bf, a3);
  hipLaunchKernelGGL(k_gconv3, dim3(196), dim3(256), 0, stream, a3, w3b, conv3_b, afbf, abf);
  hipLaunchKernelGGL(k_amean, dim3(128), dim3(64), 0, stream, afbf, amean);
  hipLaunchKernelGGL(k_embed, dim3(520), dim3(256), 0, stream, x, start_, xemb_w, xemb_b, semb_w, semb_b, xe, se);
  hipLaunchKernelGGL(k_init, dim3(512), dim3(256), 0, stream, amean, se, init_w, init_b, hbuf, cbuf);
  hipLaunchKernelGGL(k_wa, dim3(196), dim3(256), 0, stream, abf, wwbf, Wb, wabf);
  hipLaunchKernelGGL(k_cbf_xs, dim3(1024), dim3(256), 0, stream, xe, se, cbf);

  hipLaunchKernelGGL(k_loop, dim3(32), dim3(512), 0, stream,
                     uwbf, Ub, betabf, beta_b, vw, vb, wabf, afbf, xe,
                     whh_bf, wih_bf, gbias,
                     hbuf, cbuf, cbf);

  hipLaunchKernelGGL(k_comb, dim3(64, 8), dim3(256), 0, stream, cbf, cwbf, comb_b, ybf);
  hipLaunchKernelGGL(k_out, dim3(64), dim3(256), 0, stream, ybf, owbf, obias, obuf);
  hipLaunchKernelGGL(k_post, dim3(32), dim3(256), 0, stream, obuf, (float*)d_out);
}

// Round 8
// 2107.108 us; speedup vs baseline: 5.6187x; 5.4513x over previous
//
#include <hip/hip_runtime.h>

// LSTMConditioned: conv-encoder + attention-LSTM (T=64) + MDN head.
// N=128, T=64, HID=512, COMB=1024, ATT=128, K=20, D=2, FMAP=64, L=196, ODIM=121.
// Recurrence: 2 launches/step (measured-cheapest sync). stepA = attention (128 blocks,
// coalesced bf16 matvec streams). stepB = gates GEMM (32 blocks, fragment-order weights
// preloaded in regs, 4-deep LDS staging pipeline) + fused cell update.

#define TN 128
#define TT 64

typedef __attribute__((ext_vector_type(4))) float f32x4;
typedef __attribute__((ext_vector_type(8))) short bf16x8;

__device__ __forceinline__ float fsigm(float x){ return __builtin_amdgcn_rcpf(1.0f + __expf(-x)); }
__device__ __forceinline__ float ftanh(float x){ return 1.0f - 2.0f*__builtin_amdgcn_rcpf(1.0f + __expf(2.0f*x)); }
__device__ __forceinline__ unsigned short f2bf(float f){
  unsigned int u = __float_as_uint(f);
  u += 0x7fffu + ((u >> 16) & 1u);
  return (unsigned short)(u >> 16);
}
__device__ __forceinline__ float b2f(unsigned short u){ return __uint_as_float(((unsigned)u)<<16); }

// ---------------- conv1 (direct, small) ----------------
__global__ __launch_bounds__(256) void k_conv1(const float* __restrict__ xc, const float* __restrict__ w,
                                               const float* __restrict__ b, float* __restrict__ c1){
  int idx = blockIdx.x*256 + threadIdx.x;
  if (idx >= TN*16*784) return;
  int p = idx % 784, oc = (idx/784) & 15, n = idx/(784*16);
  int py = p/28, px = p%28;
  const float* src = xc + n*784;
  float acc = b[oc];
  #pragma unroll
  for (int ky=0;ky<3;ky++){
    int iy = py+ky-1; if (iy<0||iy>=28) continue;
    #pragma unroll
    for (int kx=0;kx<3;kx++){
      int ix = px+kx-1; if (ix<0||ix>=28) continue;
      acc += (src[iy*28+ix]-0.0243f)*(1.0f/0.1383f) * w[oc*9+ky*3+kx];
    }
  }
  c1[idx] = fmaxf(acc, 0.0f);
}

// ---------------- im2col for conv2 ----------------
__global__ __launch_bounds__(256) void k_im2col2(const float* __restrict__ c1, unsigned short* __restrict__ a2){
  int idx = blockIdx.x*256 + threadIdx.x;   // 62720*256 = 100352*160
  int k = idx % 160, r = idx / 160;
  unsigned short v = 0;
  if (k < 144){
    int ic = k/9, rem = k - ic*9, ky = rem/3, kx = rem - ky*3;
    int p = r % 784, n = r / 784;
    int py = p/28, px = p%28;
    int iy = py+ky-1, ix = px+kx-1;
    if (iy>=0 && iy<28 && ix>=0 && ix<28) v = f2bf(c1[(n*16+ic)*784 + iy*28+ix]);
  }
  a2[idx] = v;
}

// ---------------- conv2 GEMM ----------------
__global__ __launch_bounds__(256) void k_gconv2(const unsigned short* __restrict__ a2,
    const unsigned short* __restrict__ w2b, const float* __restrict__ b2,
    unsigned short* __restrict__ c2bf){
  int mbase = blockIdx.x*128;           // 784 blocks
  int tid = threadIdx.x, w = tid>>6, l = tid&63;
  int lr = l&15, lk = (l>>4)*8;
  __shared__ unsigned short at[128*168];
  {
    int row = tid>>1, off = (tid&1)*80;
    const unsigned short* sp = a2 + (size_t)(mbase+row)*160 + off;
    #pragma unroll
    for (int j=0;j<10;j++) *(float4*)&at[row*168 + off + j*8] = *(const float4*)(sp + j*8);
  }
  __syncthreads();
  f32x4 acc[2][2];
  #pragma unroll
  for (int mi=0;mi<2;mi++){ acc[mi][0]=(f32x4){0,0,0,0}; acc[mi][1]=(f32x4){0,0,0,0}; }
  for (int kt=0; kt<5; ++kt){
    bf16x8 b0 = *(const bf16x8*)(w2b + (0*16+lr)*160 + kt*32 + lk);
    bf16x8 b1 = *(const bf16x8*)(w2b + (1*16+lr)*160 + kt*32 + lk);
    #pragma unroll
    for (int mi=0;mi<2;mi++){
      bf16x8 afrag = *(const bf16x8*)&at[((2*w+mi)*16+lr)*168 + kt*32 + lk];
      acc[mi][0] = __builtin_amdgcn_mfma_f32_16x16x32_bf16(afrag, b0, acc[mi][0], 0,0,0);
      acc[mi][1] = __builtin_amdgcn_mfma_f32_16x16x32_bf16(afrag, b1, acc[mi][1], 0,0,0);
    }
  }
  #pragma unroll
  for (int mi=0;mi<2;mi++){
    #pragma unroll
    for (int j=0;j<2;j++){
      int oc = j*16 + lr;
      float bb = b2[oc];
      #pragma unroll
      for (int i=0;i<4;i++){
        int r = mbase + (2*w+mi)*16 + (l>>4)*4 + i;
        c2bf[(size_t)r*32 + oc] = f2bf(fmaxf(acc[mi][j][i] + bb, 0.0f));
      }
    }
  }
}

// ---------------- im2col for conv3 (stride 2) ----------------
__global__ __launch_bounds__(256) void k_im2col3(const unsigned short* __restrict__ c2bf, unsigned short* __restrict__ a3){
  int idx = blockIdx.x*256 + threadIdx.x;   // 31360*256 = 25088*320
  int k = idx % 320, r = idx / 320;
  unsigned short v = 0;
  if (k < 288){
    int ic = k/9, rem = k - ic*9, ky = rem/3, kx = rem - ky*3;
    int p = r % 196, n = r / 196;
    int py = p/14, px = p%14;
    int iy = 2*py+ky-1, ix = 2*px+kx-1;
    if (iy>=0 && iy<28 && ix>=0 && ix<28) v = c2bf[(size_t)(n*784 + iy*28+ix)*32 + ic];
  }
  a3[idx] = v;
}

// ---------------- conv3 GEMM: afbf[n][f][l] (bf16) + abf[r][f] (bf16) ----------------
__global__ __launch_bounds__(256) void k_gconv3(const unsigned short* __restrict__ a3,
    const unsigned short* __restrict__ w3b, const float* __restrict__ b3,
    unsigned short* __restrict__ afbf, unsigned short* __restrict__ abf){
  int mbase = blockIdx.x*128;           // 196 blocks
  int tid = threadIdx.x, w = tid>>6, l = tid&63;
  int lr = l&15, lk = (l>>4)*8;
  __shared__ unsigned short at[128*168];
  f32x4 acc[2][4];
  #pragma unroll
  for (int mi=0;mi<2;mi++)
    #pragma unroll
    for (int j=0;j<4;j++) acc[mi][j]=(f32x4){0,0,0,0};
  for (int kt2=0; kt2<2; ++kt2){
    {
      int row = tid>>1, off = (tid&1)*80;
      const unsigned short* sp = a3 + (size_t)(mbase+row)*320 + kt2*160 + off;
      #pragma unroll
      for (int j=0;j<10;j++) *(float4*)&at[row*168 + off + j*8] = *(const float4*)(sp + j*8);
    }
    __syncthreads();
    for (int kt=0; kt<5; ++kt){
      #pragma unroll
      for (int mi=0;mi<2;mi++){
        bf16x8 afrag = *(const bf16x8*)&at[((2*w+mi)*16+lr)*168 + kt*32 + lk];
        #pragma unroll
        for (int j=0;j<4;j++){
          bf16x8 bf = *(const bf16x8*)(w3b + (size_t)(j*16+lr)*320 + kt2*160 + kt*32 + lk);
          acc[mi][j] = __builtin_amdgcn_mfma_f32_16x16x32_bf16(afrag, bf, acc[mi][j], 0,0,0);
        }
      }
    }
    __syncthreads();
  }
  #pragma unroll
  for (int mi=0;mi<2;mi++){
    #pragma unroll
    for (int j=0;j<4;j++){
      int oc = j*16 + lr;
      float bb = b3[oc];
      #pragma unroll
      for (int i=0;i<4;i++){
        int r = mbase + (2*w+mi)*16 + (l>>4)*4 + i;
        int n = r/196, p = r - n*196;
        float v = ftanh(acc[mi][j][i] + bb);
        unsigned short vb16 = f2bf(v);
        afbf[(size_t)(n*64+oc)*196 + p] = vb16;
        abf[(size_t)r*64 + oc] = vb16;
      }
    }
  }
}

__global__ __launch_bounds__(64) void k_amean(const unsigned short* __restrict__ afbf, float* __restrict__ amean){
  int n = blockIdx.x, f = threadIdx.x;
  const unsigned short* row = afbf + (size_t)(n*64+f)*196;
  float s = 0;
  for (int l=0;l<196;l++) s += b2f(row[l]);
  amean[n*64+f] = s * (1.0f/196.0f);
}

// ---------------- embeddings / init ----------------
__global__ __launch_bounds__(256) void k_embed(const float* __restrict__ x, const float* __restrict__ start,
    const float* __restrict__ xw, const float* __restrict__ xb,
    const float* __restrict__ sw, const float* __restrict__ sb,
    float* __restrict__ xe, float* __restrict__ se){
  int idx = blockIdx.x*256 + threadIdx.x;
  if (idx < TN*TT*16){
    int j = idx & 15, t = (idx>>4) & 63, n = idx>>10;
    float acc = xb[j];
    if (t > 0){
      const float* xp = x + (n*TT + t-1)*2;
      acc += xp[0]*xw[j*2] + xp[1]*xw[j*2+1];
    }
    xe[idx] = ftanh(acc);
  } else if (idx < TN*TT*16 + TN*16){
    int k2 = idx - TN*TT*16;
    int j = k2 & 15, n = k2 >> 4;
    float acc = sb[j] + start[n*2]*sw[j*2] + start[n*2+1]*sw[j*2+1];
    se[k2] = ftanh(acc);
  }
}

__global__ __launch_bounds__(256) void k_init(const float* __restrict__ amean, const float* __restrict__ se,
    const float* __restrict__ w, const float* __restrict__ b,
    unsigned short* __restrict__ hbfA, float* __restrict__ cbuf){
  int idx = blockIdx.x*256 + threadIdx.x;
  if (idx >= TN*1024) return;
  int o = idx & 1023, n = idx >> 10;
  const float* wr = w + o*80;
  float acc = b[o];
  for (int k2=0;k2<64;k2++) acc += amean[n*64+k2]*wr[k2];
  for (int k2=0;k2<16;k2++) acc += se[n*16+k2]*wr[64+k2];
  float v = ftanh(acc);
  if (o & 1) cbuf[n*512 + (o>>1)] = v;
  else       hbfA[n*512 + (o>>1)] = f2bf(v);
}

// ---------------- weight prep ----------------
// wgf: gates weights in MFMA fragment order: frag (g,b,kt) at ((g*32+b)*19+kt)*512,
// lane l elem j = W[g*512+b*16+(l&15)][kt*32+(l>>4)*8+j], W = [Whh | Wih(pad 96)].
__global__ __launch_bounds__(256) void k_prep(
    const float* __restrict__ Whh, const float* __restrict__ Wih,
    const float* __restrict__ bih, const float* __restrict__ bhh,
    const float* __restrict__ comb_w, const float* __restrict__ out_w, const float* __restrict__ out_b,
    const float* __restrict__ Uw, const float* __restrict__ beta_w, const float* __restrict__ Ww,
    const float* __restrict__ conv2_w, const float* __restrict__ conv3_w,
    unsigned short* __restrict__ wgf, float* __restrict__ gbias,
    unsigned short* __restrict__ cwbf, unsigned short* __restrict__ owbf, float* __restrict__ obias,
    unsigned short* __restrict__ uwbf, unsigned short* __restrict__ betabf, unsigned short* __restrict__ wwbf,
    unsigned short* __restrict__ w2b, unsigned short* __restrict__ w3b){
  int idx = blockIdx.x*256 + threadIdx.x;
  if (idx < 1245184){
    int fragi = idx >> 9;
    int lane8 = idx & 511;
    int lane = lane8 >> 3, j = lane8 & 7;
    int g = fragi / 608;
    int rem = fragi - g*608;
    int b = rem / 19, kt = rem - b*19;
    int row = g*512 + b*16 + (lane & 15);
    int col = kt*32 + (lane >> 4)*8 + j;
    float v = 0.f;
    if (col < 512) v = Whh[(size_t)row*512 + col];
    else { int c2 = col - 512; if (c2 < 80) v = Wih[(size_t)row*80 + c2]; }
    wgf[idx] = f2bf(v);
    return;
  }
  idx -= 1245184;
  if (idx < 2048){ gbias[idx] = bih[idx]+bhh[idx]; return; }
  idx -= 2048;
  if (idx < 622592){ cwbf[idx] = f2bf(comb_w[idx]); return; }
  idx -= 622592;
  if (idx < 131072){ int o = idx>>10, k2 = idx & 1023; owbf[idx] = (o<121)? f2bf(out_w[o*1024+k2]) : (unsigned short)0; return; }
  idx -= 131072;
  if (idx < 128){ obias[idx] = (idx<121)? out_b[idx] : 0.0f; return; }
  idx -= 128;
  if (idx < 65536){ uwbf[idx] = f2bf(Uw[idx]); return; }
  idx -= 65536;
  if (idx < 32768){ betabf[idx] = f2bf(beta_w[idx]); return; }
  idx -= 32768;
  if (idx < 8192){ wwbf[idx] = f2bf(Ww[idx]); return; }
  idx -= 8192;
  if (idx < 5120){ int o = idx/160, k2 = idx - o*160; w2b[idx] = (k2<144)? f2bf(conv2_w[o*144+k2]) : (unsigned short)0; return; }
  idx -= 5120;
  if (idx < 20480){ int o = idx/320, k2 = idx - o*320; w3b[idx] = (k2<288)? f2bf(conv3_w[o*288+k2]) : (unsigned short)0; return; }
}

// ---------------- W_a = a @ Ww.T + Wb (MFMA), stored bf16 [n][l][att] ----------------
__global__ __launch_bounds__(256) void k_wa(const unsigned short* __restrict__ abf,
    const unsigned short* __restrict__ wwbf, const float* __restrict__ Wb,
    unsigned short* __restrict__ wabf){
  int mbase = blockIdx.x*128;
  int tid = threadIdx.x, w = tid>>6, l = tid&63;
  int lr = l & 15, lk = (l>>4)*8;
  __shared__ unsigned short at[128*40];
  f32x4 acc[8][2];
  #pragma unroll
  for (int m=0;m<8;m++){ acc[m][0] = (f32x4){0,0,0,0}; acc[m][1] = (f32x4){0,0,0,0}; }
  for (int kt=0; kt<2; ++kt){
    int row = tid>>1, half = (tid&1)*16;
    const unsigned short* sp = abf + (mbase+row)*64 + kt*32 + half;
    *(float4*)&at[row*40 + half]     = *(const float4*)sp;
    *(float4*)&at[row*40 + half + 8] = *(const float4*)(sp + 8);
    __syncthreads();
    bf16x8 b0 = *(const bf16x8*)(wwbf + ((2*w+0)*16 + lr)*64 + kt*32 + lk);
    bf16x8 b1 = *(const bf16x8*)(wwbf + ((2*w+1)*16 + lr)*64 + kt*32 + lk);
    #pragma unroll
    for (int m=0;m<8;m++){
      bf16x8 afrag = *(const bf16x8*)&at[(m*16+lr)*40 + lk];
      acc[m][0] = __builtin_amdgcn_mfma_f32_16x16x32_bf16(afrag, b0, acc[m][0], 0,0,0);
      acc[m][1] = __builtin_amdgcn_mfma_f32_16x16x32_bf16(afrag, b1, acc[m][1], 0,0,0);
    }
    __syncthreads();
  }
  #pragma unroll
  for (int m=0;m<8;m++){
    #pragma unroll
    for (int j=0;j<2;j++){
      int att = (2*w+j)*16 + lr;
      float wb = Wb[att];
      #pragma unroll
      for (int i=0;i<4;i++){
        int arow = mbase + m*16 + (l>>4)*4 + i;
        int n = arow/196, l2 = arow - n*196;
        wabf[((size_t)n*196 + l2)*128 + att] = f2bf(acc[m][j][i] + wb);
      }
    }
  }
}

// ---------------- step A: attention (128 blocks, 256 thr), coalesced bf16 streams ----------------
__global__ __launch_bounds__(256) void k_stepA(int t,
    const unsigned short* __restrict__ hbf_in,
    const unsigned short* __restrict__ uwbf, const float* __restrict__ Ub,
    const unsigned short* __restrict__ betabf, const float* __restrict__ beta_b,
    const float* __restrict__ vw, const float* __restrict__ vb,
    const unsigned short* __restrict__ wabf, const unsigned short* __restrict__ afbf,
    unsigned short* __restrict__ ubf_all, unsigned short* __restrict__ cbf)
{
  const int n = blockIdx.x, tid = threadIdx.x;
  __shared__ __align__(16) float hs[512];
  __shared__ __align__(16) float Uh[128];
  __shared__ __align__(16) float vws[128];
  __shared__ float bsig[64];
  __shared__ float ew[196];
  __shared__ float red[16];
  __shared__ float up[2][128];
  __shared__ float qp[4][64];
  hs[tid]       = b2f(hbf_in[n*512 + tid]);
  hs[256 + tid] = b2f(hbf_in[n*512 + 256 + tid]);
  if (tid < 128) vws[tid] = vw[tid];
  const float vb0 = vb[0];
  __syncthreads();
  // Uh partials: (att, k-half); per-lane contiguous bf16 stream
  {
    int att = tid & 127, half = tid >> 7;
    const unsigned short* uw = uwbf + (size_t)att*512 + half*256;
    const float* hh = hs + half*256;
    float acc = 0.f;
    #pragma unroll 4
    for (int k=0;k<256;k+=8){
      bf16x8 v = *(const bf16x8*)(uw + k);
      acc += hh[k+0]*b2f(v[0]) + hh[k+1]*b2f(v[1]) + hh[k+2]*b2f(v[2]) + hh[k+3]*b2f(v[3])
           + hh[k+4]*b2f(v[4]) + hh[k+5]*b2f(v[5]) + hh[k+6]*b2f(v[6]) + hh[k+7]*b2f(v[7]);
    }
    up[half][att] = acc;
  }
  // beta partials: (f, k-quarter)
  {
    int f = tid & 63, q = tid >> 6;
    const unsigned short* bw = betabf + (size_t)f*512 + q*128;
    const float* hh = hs + q*128;
    float acc = 0.f;
    #pragma unroll 4
    for (int k=0;k<128;k+=8){
      bf16x8 v = *(const bf16x8*)(bw + k);
      acc += hh[k+0]*b2f(v[0]) + hh[k+1]*b2f(v[1]) + hh[k+2]*b2f(v[2]) + hh[k+3]*b2f(v[3])
           + hh[k+4]*b2f(v[4]) + hh[k+5]*b2f(v[5]) + hh[k+6]*b2f(v[6]) + hh[k+7]*b2f(v[7]);
    }
    qp[q][f] = acc;
  }
  __syncthreads();
  if (tid < 128) Uh[tid] = Ub[tid] + up[0][tid] + up[1][tid];
  else if (tid < 192){
    int f = tid-128;
    bsig[f] = fsigm(beta_b[f] + qp[0][f]+qp[1][f]+qp[2][f]+qp[3][f]);
  }
  __syncthreads();
  // e[l]: one thread per l, contiguous 256B wabf row
  float ev = -1e30f;
  if (tid < 196){
    const unsigned short* wr = wabf + ((size_t)n*196 + tid)*128;
    float a = vb0;
    #pragma unroll 4
    for (int k=0;k<128;k+=8){
      bf16x8 wv = *(const bf16x8*)(wr + k);
      a += vws[k+0]*ftanh(b2f(wv[0]) + Uh[k+0]) + vws[k+1]*ftanh(b2f(wv[1]) + Uh[k+1])
         + vws[k+2]*ftanh(b2f(wv[2]) + Uh[k+2]) + vws[k+3]*ftanh(b2f(wv[3]) + Uh[k+3])
         + vws[k+4]*ftanh(b2f(wv[4]) + Uh[k+4]) + vws[k+5]*ftanh(b2f(wv[5]) + Uh[k+5])
         + vws[k+6]*ftanh(b2f(wv[6]) + Uh[k+6]) + vws[k+7]*ftanh(b2f(wv[7]) + Uh[k+7]);
    }
    ev = a;
  }
  float m = ev;
  #pragma unroll
  for (int off=32; off>0; off>>=1) m = fmaxf(m, __shfl_xor(m, off));
  if ((tid&63)==0) red[tid>>6] = m;
  __syncthreads();
  float mx = fmaxf(fmaxf(red[0],red[1]), fmaxf(red[2],red[3]));
  float ex = (tid<196) ? __expf(ev - mx) : 0.0f;
  float ss = ex;
  #pragma unroll
  for (int off=32; off>0; off>>=1) ss += __shfl_xor(ss, off);
  if ((tid&63)==0) red[8+(tid>>6)] = ss;
  if (tid<196) ew[tid] = ex;
  __syncthreads();
  float inv = __builtin_amdgcn_rcpf(red[8]+red[9]+red[10]+red[11]);
  // z partials: (f, l-quarter of 49), per-lane contiguous afbf row segment
  {
    int f = tid & 63, q = tid >> 6;
    const unsigned short* an = afbf + (size_t)n*12544 + (size_t)f*196 + q*49;
    const float* el = ew + q*49;
    float acc = 0.f;
    #pragma unroll 7
    for (int i2=0;i2<49;i2++) acc += el[i2]*b2f(an[i2]);
    qp[q][f] = acc;
  }
  __syncthreads();
  if (tid < 64){
    float z = bsig[tid]*(qp[0][tid]+qp[1][tid]+qp[2][tid]+qp[3][tid])*inv;
    unsigned short zb = f2bf(z);
    ubf_all[((size_t)t*TN + n)*96 + 16 + tid] = zb;
    cbf[((size_t)n*TT + t)*608 + 512 + tid] = zb;
  }
}

// ---------------- step B: gates GEMM + cell update (32 blocks, 256 thr) ----------------
__global__ __launch_bounds__(256) void k_stepB(int t,
    const unsigned short* __restrict__ hin, unsigned short* __restrict__ hout,
    const unsigned short* __restrict__ ubf_all,
    const unsigned short* __restrict__ wgf, const float* __restrict__ gbias,
    float* __restrict__ cbuf, unsigned short* __restrict__ cbf)
{
  const int b = blockIdx.x, tid = threadIdx.x;
  const int w = tid>>6, l = tid&63, lr = l&15, li = l>>4, lk = li*8;
  __shared__ unsigned short at2[2][128*40];
  __shared__ float gsh[4][128][16];
  const unsigned short* ub = ubf_all + (size_t)t*TN*96;
  // preload this wave's 19 B-fragments (contiguous 1KB each)
  bf16x8 wreg[19];
  {
    const unsigned short* wp = wgf + ((size_t)(w*32 + b)*19)*512 + l*8;
    #pragma unroll
    for (int i=0;i<19;i++) wreg[i] = *(const bf16x8*)(wp + i*512);
  }
  const int srow = tid>>1, shalf = (tid&1)*16;
  f32x4 acc[8];
  #pragma unroll
  for (int m=0;m<8;m++) acc[m] = (f32x4){0,0,0,0};
  float4 rx[4], ry[4];
  #pragma unroll
  for (int i=0;i<4;i++){
    const unsigned short* sp = (i<16) ? (hin + srow*512 + i*32 + shalf)
                                      : (ub + srow*96 + (i-16)*32 + shalf);
    rx[i] = *(const float4*)sp; ry[i] = *(const float4*)(sp + 8);
  }
  {
    unsigned short* d = &at2[0][srow*40 + shalf];
    *(float4*)d = rx[0]; *(float4*)(d+8) = ry[0];
  }
  __syncthreads();
  #pragma unroll
  for (int kt=0; kt<19; ++kt){
    if (kt+1 < 19){
      unsigned short* d = &at2[(kt+1)&1][srow*40 + shalf];
      *(float4*)d = rx[(kt+1)&3]; *(float4*)(d+8) = ry[(kt+1)&3];
    }
    if (kt+4 < 19){
      int kl = kt+4;
      const unsigned short* sp = (kl<16) ? (hin + srow*512 + kl*32 + shalf)
                                         : (ub + srow*96 + (kl-16)*32 + shalf);
      rx[kt&3] = *(const float4*)sp; ry[kt&3] = *(const float4*)(sp + 8);
    }
    #pragma unroll
    for (int m=0;m<8;m++){
      bf16x8 a = *(const bf16x8*)&at2[kt&1][(m*16+lr)*40 + lk];
      acc[m] = __builtin_amdgcn_mfma_f32_16x16x32_bf16(a, wreg[kt], acc[m], 0,0,0);
    }
    __syncthreads();
  }
  float gb = gbias[w*512 + b*16 + lr];
  #pragma unroll
  for (int m=0;m<8;m++)
    #pragma unroll
    for (int i=0;i<4;i++)
      gsh[w][m*16 + li*4 + i][lr] = acc[m][i] + gb;
  __syncthreads();
  #pragma unroll
  for (int e=0;e<8;++e){
    int c = tid*8 + e;
    int nn = c>>4, j = c&15;
    int hidx = b*16 + j;
    float gi = gsh[0][nn][j], gf = gsh[1][nn][j], gg = gsh[2][nn][j], go = gsh[3][nn][j];
    float cc = cbuf[nn*512 + hidx];
    float cs = fsigm(gf)*cc + fsigm(gi)*ftanh(gg);
    float h  = fsigm(go)*ftanh(cs);
    cbuf[nn*512 + hidx] = cs;
    unsigned short hb = f2bf(h);
    hout[nn*512 + hidx] = hb;
    cbf[((size_t)nn*TT + t)*608 + hidx] = hb;
  }
}

// ---------------- comb-input xe/se slices + ubf xe/pad prefill ----------------
__global__ __launch_bounds__(256) void k_cbf_xs(const float* __restrict__ xe, const float* __restrict__ se,
                                                unsigned short* __restrict__ cbf,
                                                unsigned short* __restrict__ ubf_all){
  int idx = blockIdx.x*256 + threadIdx.x;   // 2048 blocks: TN*TT*64
  if (idx >= TN*TT*64) return;
  int j = idx & 63, r = idx >> 6;
  int n = r >> 6, t = r & 63;
  if (j < 16)      cbf[(size_t)r*608 + 576 + j] = f2bf(xe[r*16 + j]);
  else if (j < 32) cbf[(size_t)r*608 + 592 + (j-16)] = f2bf(se[n*16 + (j-16)]);
  else if (j < 48) ubf_all[((size_t)t*TN + n)*96 + (j-32)] = f2bf(xe[r*16 + (j-32)]);
  else             ubf_all[((size_t)t*TN + n)*96 + 80 + (j-48)] = 0;
}

// ---------------- comb GEMM ----------------
__global__ __launch_bounds__(256) void k_comb(const unsigned short* __restrict__ cbf,
    const unsigned short* __restrict__ cwbf, const float* __restrict__ comb_b,
    unsigned short* __restrict__ ybf){
  int mbase = blockIdx.x*128, obase = blockIdx.y*128;
  int tid = threadIdx.x, w = tid>>6, l = tid&63;
  int lr = l&15, lk = (l>>4)*8;
  __shared__ unsigned short at[128*40];
  f32x4 acc[8][2];
  #pragma unroll
  for (int m=0;m<8;m++){ acc[m][0] = (f32x4){0,0,0,0}; acc[m][1] = (f32x4){0,0,0,0}; }
  for (int kt=0; kt<19; ++kt){
    int row = tid>>1, half = (tid&1)*16;
    const unsigned short* sp = cbf + (size_t)(mbase+row)*608 + kt*32 + half;
    *(float4*)&at[row*40 + half]     = *(const float4*)sp;
    *(float4*)&at[row*40 + half + 8] = *(const float4*)(sp + 8);
    __syncthreads();
    bf16x8 b0 = *(const bf16x8*)(cwbf + (size_t)(obase + (2*w+0)*16 + lr)*608 + kt*32 + lk);
    bf16x8 b1 = *(const bf16x8*)(cwbf + (size_t)(obase + (2*w+1)*16 + lr)*608 + kt*32 + lk);
    #pragma unroll
    for (int m=0;m<8;m++){
      bf16x8 afrag = *(const bf16x8*)&at[(m*16+lr)*40 + lk];
      acc[m][0] = __builtin_amdgcn_mfma_f32_16x16x32_bf16(afrag, b0, acc[m][0], 0,0,0);
      acc[m][1] = __builtin_amdgcn_mfma_f32_16x16x32_bf16(afrag, b1, acc[m][1], 0,0,0);
    }
    __syncthreads();
  }
  #pragma unroll
  for (int m=0;m<8;m++){
    #pragma unroll
    for (int j=0;j<2;j++){
      int o = obase + (2*w+j)*16 + lr;
      float cb = comb_b[o];
      #pragma unroll
      for (int i=0;i<4;i++){
        int r = mbase + m*16 + (l>>4)*4 + i;
        ybf[(size_t)r*1024 + o] = f2bf(ftanh(acc[m][j][i] + cb));
      }
    }
  }
}

// ---------------- out GEMM ----------------
__global__ __launch_bounds__(256) void k_out(const unsigned short* __restrict__ ybf,
    const unsigned short* __restrict__ owbf, const float* __restrict__ obias,
    float* __restrict__ obuf){
  int mbase = blockIdx.x*128;
  int tid = threadIdx.x, w = tid>>6, l = tid&63;
  int lr = l&15, lk = (l>>4)*8;
  __shared__ unsigned short at[128*40];
  f32x4 acc[8][2];
  #pragma unroll
  for (int m=0;m<8;m++){ acc[m][0] = (f32x4){0,0,0,0}; acc[m][1] = (f32x4){0,0,0,0}; }
  for (int kt=0; kt<32; ++kt){
    int row = tid>>1, half = (tid&1)*16;
    const unsigned short* sp = ybf + (size_t)(mbase+row)*1024 + kt*32 + half;
    *(float4*)&at[row*40 + half]     = *(const float4*)sp;
    *(float4*)&at[row*40 + half + 8] = *(const float4*)(sp + 8);
    __syncthreads();
    bf16x8 b0 = *(const bf16x8*)(owbf + ((2*w+0)*16 + lr)*1024 + kt*32 + lk);
    bf16x8 b1 = *(const bf16x8*)(owbf + ((2*w+1)*16 + lr)*1024 + kt*32 + lk);
    #pragma unroll
    for (int m=0;m<8;m++){
      bf16x8 afrag = *(const bf16x8*)&at[(m*16+lr)*40 + lk];
      acc[m][0] = __builtin_amdgcn_mfma_f32_16x16x32_bf16(afrag, b0, acc[m][0], 0,0,0);
      acc[m][1] = __builtin_amdgcn_mfma_f32_16x16x32_bf16(afrag, b1, acc[m][1], 0,0,0);
    }
    __syncthreads();
  }
  #pragma unroll
  for (int m=0;m<8;m++){
    #pragma unroll
    for (int j=0;j<2;j++){
      int o = (2*w+j)*16 + lr;
      float ob = obias[o];
      #pragma unroll
      for (int i=0;i<4;i++){
        int r = mbase + m*16 + (l>>4)*4 + i;
        obuf[(size_t)r*128 + o] = acc[m][j][i] + ob;
      }
    }
  }
}

// ---------------- postprocess ----------------
__global__ __launch_bounds__(256) void k_post(const float* __restrict__ obuf, float* __restrict__ out){
  int r = blockIdx.x*256 + threadIdx.x;
  if (r >= TN*TT) return;
  const float* row = obuf + (size_t)r*128;
  float mx = -1e30f;
  #pragma unroll
  for (int k2=0;k2<20;k2++) mx = fmaxf(mx, row[k2]);
  float e[20]; float s = 0;
  #pragma unroll
  for (int k2=0;k2<20;k2++){ e[k2] = __expf(row[k2]-mx); s += e[k2]; }
  float inv = __builtin_amdgcn_rcpf(s);
  float* mixo  = out;
  float* meano = out + 163840;
  float* scaleo= out + 491520;
  float* corro = out + 819200;
  float* vlogo = out + 983040;
  #pragma unroll
  for (int k2=0;k2<20;k2++) mixo[r*20+k2] = e[k2]*inv;
  #pragma unroll
  for (int j=0;j<40;j++) meano[r*40+j] = row[20+j];
  #pragma unroll
  for (int j=0;j<40;j++) scaleo[r*40+j] = __expf(row[60+j]);
  #pragma unroll
  for (int k2=0;k2<20;k2++) corro[r*20+k2] = ftanh(row[100+k2]);
  vlogo[r] = row[120];
}

extern "C" void kernel_launch(void* const* d_in, const int* in_sizes, int n_in,
                              void* d_out, int out_size, void* d_ws, size_t ws_size,
                              hipStream_t stream){
  const float* x       = (const float*)d_in[0];
  const float* x_canv  = (const float*)d_in[1];
  const float* start_  = (const float*)d_in[2];
  const float* conv1_w = (const float*)d_in[3];
  const float* conv1_b = (const float*)d_in[4];
  const float* conv2_w = (const float*)d_in[5];
  const float* conv2_b = (const float*)d_in[6];
  const float* conv3_w = (const float*)d_in[7];
  const float* conv3_b = (const float*)d_in[8];
  const float* init_w  = (const float*)d_in[9];
  const float* init_b  = (const float*)d_in[10];
  const float* Uw      = (const float*)d_in[11];
  const float* Ub      = (const float*)d_in[12];
  const float* Ww      = (const float*)d_in[13];
  const float* Wb      = (const float*)d_in[14];
  const float* vw      = (const float*)d_in[15];
  const float* vb      = (const float*)d_in[16];
  const float* beta_w  = (const float*)d_in[17];
  const float* beta_b  = (const float*)d_in[18];
  const float* xemb_w  = (const float*)d_in[19];
  const float* xemb_b  = (const float*)d_in[20];
  const float* semb_w  = (const float*)d_in[21];
  const float* semb_b  = (const float*)d_in[22];
  const float* Wih     = (const float*)d_in[23];
  const float* Whh     = (const float*)d_in[24];
  const float* bih     = (const float*)d_in[25];
  const float* bhh     = (const float*)d_in[26];
  const float* comb_w  = (const float*)d_in[27];
  const float* comb_b  = (const float*)d_in[28];
  const float* out_w   = (const float*)d_in[29];
  const float* out_b   = (const float*)d_in[30];
  (void)in_sizes; (void)n_in; (void)out_size; (void)ws_size;

  char* wsb = (char*)d_ws;
  size_t off = 0;
  auto alloc = [&](size_t bytes)->char*{
    char* p = wsb + off;
    off = (off + bytes + 255) & ~(size_t)255;
    return p;
  };
  float*          c1     = (float*)alloc((size_t)TN*16*784*4);
  unsigned short* a2     = (unsigned short*)alloc((size_t)100352*160*2);  // a3 aliases a2
  unsigned short* a3     = a2;
  unsigned short* c2bf   = (unsigned short*)alloc((size_t)100352*32*2);
  unsigned short* afbf   = (unsigned short*)alloc((size_t)TN*64*196*2);
  unsigned short* abf    = (unsigned short*)alloc((size_t)TN*196*64*2);
  float*          amean  = (float*)alloc((size_t)TN*64*4);
  float*          xe     = (float*)alloc((size_t)TN*TT*16*4);
  float*          se     = (float*)alloc((size_t)TN*16*4);
  unsigned short* wabf   = (unsigned short*)alloc((size_t)TN*196*128*2);
  float*          cbuf   = (float*)alloc((size_t)TN*512*4);
  unsigned short* hbfA   = (unsigned short*)alloc((size_t)TN*512*2);
  unsigned short* hbfB   = (unsigned short*)alloc((size_t)TN*512*2);
  unsigned short* ubf_all= (unsigned short*)alloc((size_t)TT*TN*96*2);
  unsigned short* cbf    = (unsigned short*)alloc((size_t)TN*TT*608*2);
  unsigned short* ybf    = (unsigned short*)alloc((size_t)TN*TT*1024*2);
  float*          obuf   = (float*)alloc((size_t)TN*TT*128*4);
  unsigned short* wgf    = (unsigned short*)alloc((size_t)1245184*2);
  float*          gbias  = (float*)alloc((size_t)2048*4);
  unsigned short* cwbf   = (unsigned short*)alloc((size_t)1024*608*2);
  unsigned short* owbf   = (unsigned short*)alloc((size_t)128*1024*2);
  float*          obias  = (float*)alloc((size_t)128*4);
  unsigned short* uwbf   = (unsigned short*)alloc((size_t)128*512*2);
  unsigned short* betabf = (unsigned short*)alloc((size_t)64*512*2);
  unsigned short* wwbf   = (unsigned short*)alloc((size_t)128*64*2);
  unsigned short* w2b    = (unsigned short*)alloc((size_t)32*160*2);
  unsigned short* w3b    = (unsigned short*)alloc((size_t)64*320*2);

  hipLaunchKernelGGL(k_conv1, dim3(6272), dim3(256), 0, stream, x_canv, conv1_w, conv1_b, c1);
  hipLaunchKernelGGL(k_prep, dim3(8334), dim3(256), 0, stream,
                     Whh, Wih, bih, bhh, comb_w, out_w, out_b, Uw, beta_w, Ww, conv2_w, conv3_w,
                     wgf, gbias, cwbf, owbf, obias, uwbf, betabf, wwbf, w2b, w3b);
  hipLaunchKernelGGL(k_im2col2, dim3(62720), dim3(256), 0, stream, c1, a2);
  hipLaunchKernelGGL(k_gconv2, dim3(784), dim3(256), 0, stream, a2, w2b, conv2_b, c2bf);
  hipLaunchKernelGGL(k_im2col3, dim3(31360), dim3(256), 0, stream, c2bf, a3);
  hipLaunchKernelGGL(k_gconv3, dim3(196), dim3(256), 0, stream, a3, w3b, conv3_b, afbf, abf);
  hipLaunchKernelGGL(k_amean, dim3(128), dim3(64), 0, stream, afbf, amean);
  hipLaunchKernelGGL(k_embed, dim3(520), dim3(256), 0, stream, x, start_, xemb_w, xemb_b, semb_w, semb_b, xe, se);
  hipLaunchKernelGGL(k_init, dim3(512), dim3(256), 0, stream, amean, se, init_w, init_b, hbfA, cbuf);
  hipLaunchKernelGGL(k_wa, dim3(196), dim3(256), 0, stream, abf, wwbf, Wb, wabf);
  hipLaunchKernelGGL(k_cbf_xs, dim3(2048), dim3(256), 0, stream, xe, se, cbf, ubf_all);

  for (int t = 0; t < TT; ++t){
    unsigned short* hin  = (t & 1) ? hbfB : hbfA;
    unsigned short* hout = (t & 1) ? hbfA : hbfB;
    hipLaunchKernelGGL(k_stepA, dim3(128), dim3(256), 0, stream, t,
                       hin, uwbf, Ub, betabf, beta_b, vw, vb, wabf, afbf, ubf_all, cbf);
    hipLaunchKernelGGL(k_stepB, dim3(32), dim3(256), 0, stream, t,
                       hin, hout, ubf_all, wgf, gbias, cbuf, cbf);
  }

  hipLaunchKernelGGL(k_comb, dim3(64, 8), dim3(256), 0, stream, cbf, cwbf, comb_b, ybf);
  hipLaunchKernelGGL(k_out, dim3(64), dim3(256), 0, stream, ybf, owbf, obias, obuf);
  hipLaunchKernelGGL(k_post, dim3(32), dim3(256), 0, stream, obuf, (float*)d_out);
}

// Round 9
// 1669.833 us; speedup vs baseline: 7.0901x; 1.2619x over previous
//
#include <hip/hip_runtime.h>

// LSTMConditioned: conv-encoder + attention-LSTM (T=64) + MDN head.
// N=128, T=64, HID=512, COMB=1024, ATT=128, K=20, D=2, FMAP=64, L=196, ODIM=121.
// Recurrence: 2 launches/step. stepA (160 blocks x 512 thr) = attention (blocks 0-127,
// fine-split phases) PARALLEL WITH gates Whh-part GEMM (blocks 128-159 -> gpart f32).
// stepB (32 blocks x 256 thr) = z-part GEMM (3 K-tiles) + fused cell update.

#define TN 128
#define TT 64

typedef __attribute__((ext_vector_type(4))) float f32x4;
typedef __attribute__((ext_vector_type(8))) short bf16x8;

__device__ __forceinline__ float fsigm(float x){ return __builtin_amdgcn_rcpf(1.0f + __expf(-x)); }
__device__ __forceinline__ float ftanh(float x){ return 1.0f - 2.0f*__builtin_amdgcn_rcpf(1.0f + __expf(2.0f*x)); }
__device__ __forceinline__ unsigned short f2bf(float f){
  unsigned int u = __float_as_uint(f);
  u += 0x7fffu + ((u >> 16) & 1u);
  return (unsigned short)(u >> 16);
}
__device__ __forceinline__ float b2f(unsigned short u){ return __uint_as_float(((unsigned)u)<<16); }

// ---------------- conv1 (direct, small) ----------------
__global__ __launch_bounds__(256) void k_conv1(const float* __restrict__ xc, const float* __restrict__ w,
                                               const float* __restrict__ b, float* __restrict__ c1){
  int idx = blockIdx.x*256 + threadIdx.x;
  if (idx >= TN*16*784) return;
  int p = idx % 784, oc = (idx/784) & 15, n = idx/(784*16);
  int py = p/28, px = p%28;
  const float* src = xc + n*784;
  float acc = b[oc];
  #pragma unroll
  for (int ky=0;ky<3;ky++){
    int iy = py+ky-1; if (iy<0||iy>=28) continue;
    #pragma unroll
    for (int kx=0;kx<3;kx++){
      int ix = px+kx-1; if (ix<0||ix>=28) continue;
      acc += (src[iy*28+ix]-0.0243f)*(1.0f/0.1383f) * w[oc*9+ky*3+kx];
    }
  }
  c1[idx] = fmaxf(acc, 0.0f);
}

// ---------------- im2col for conv2 ----------------
__global__ __launch_bounds__(256) void k_im2col2(const float* __restrict__ c1, unsigned short* __restrict__ a2){
  int idx = blockIdx.x*256 + threadIdx.x;   // 62720*256 = 100352*160
  int k = idx % 160, r = idx / 160;
  unsigned short v = 0;
  if (k < 144){
    int ic = k/9, rem = k - ic*9, ky = rem/3, kx = rem - ky*3;
    int p = r % 784, n = r / 784;
    int py = p/28, px = p%28;
    int iy = py+ky-1, ix = px+kx-1;
    if (iy>=0 && iy<28 && ix>=0 && ix<28) v = f2bf(c1[(n*16+ic)*784 + iy*28+ix]);
  }
  a2[idx] = v;
}

// ---------------- conv2 GEMM ----------------
__global__ __launch_bounds__(256) void k_gconv2(const unsigned short* __restrict__ a2,
    const unsigned short* __restrict__ w2b, const float* __restrict__ b2,
    unsigned short* __restrict__ c2bf){
  int mbase = blockIdx.x*128;           // 784 blocks
  int tid = threadIdx.x, w = tid>>6, l = tid&63;
  int lr = l&15, lk = (l>>4)*8;
  __shared__ unsigned short at[128*168];
  {
    int row = tid>>1, off = (tid&1)*80;
    const unsigned short* sp = a2 + (size_t)(mbase+row)*160 + off;
    #pragma unroll
    for (int j=0;j<10;j++) *(float4*)&at[row*168 + off + j*8] = *(const float4*)(sp + j*8);
  }
  __syncthreads();
  f32x4 acc[2][2];
  #pragma unroll
  for (int mi=0;mi<2;mi++){ acc[mi][0]=(f32x4){0,0,0,0}; acc[mi][1]=(f32x4){0,0,0,0}; }
  for (int kt=0; kt<5; ++kt){
    bf16x8 b0 = *(const bf16x8*)(w2b + (0*16+lr)*160 + kt*32 + lk);
    bf16x8 b1 = *(const bf16x8*)(w2b + (1*16+lr)*160 + kt*32 + lk);
    #pragma unroll
    for (int mi=0;mi<2;mi++){
      bf16x8 afrag = *(const bf16x8*)&at[((2*w+mi)*16+lr)*168 + kt*32 + lk];
      acc[mi][0] = __builtin_amdgcn_mfma_f32_16x16x32_bf16(afrag, b0, acc[mi][0], 0,0,0);
      acc[mi][1] = __builtin_amdgcn_mfma_f32_16x16x32_bf16(afrag, b1, acc[mi][1], 0,0,0);
    }
  }
  #pragma unroll
  for (int mi=0;mi<2;mi++){
    #pragma unroll
    for (int j=0;j<2;j++){
      int oc = j*16 + lr;
      float bb = b2[oc];
      #pragma unroll
      for (int i=0;i<4;i++){
        int r = mbase + (2*w+mi)*16 + (l>>4)*4 + i;
        c2bf[(size_t)r*32 + oc] = f2bf(fmaxf(acc[mi][j][i] + bb, 0.0f));
      }
    }
  }
}

// ---------------- im2col for conv3 (stride 2) ----------------
__global__ __launch_bounds__(256) void k_im2col3(const unsigned short* __restrict__ c2bf, unsigned short* __restrict__ a3){
  int idx = blockIdx.x*256 + threadIdx.x;   // 31360*256 = 25088*320
  int k = idx % 320, r = idx / 320;
  unsigned short v = 0;
  if (k < 288){
    int ic = k/9, rem = k - ic*9, ky = rem/3, kx = rem - ky*3;
    int p = r % 196, n = r / 196;
    int py = p/14, px = p%14;
    int iy = 2*py+ky-1, ix = 2*px+kx-1;
    if (iy>=0 && iy<28 && ix>=0 && ix<28) v = c2bf[(size_t)(n*784 + iy*28+ix)*32 + ic];
  }
  a3[idx] = v;
}

// ---------------- conv3 GEMM: afbf[n][f][l] (bf16) + abf[r][f] (bf16) ----------------
__global__ __launch_bounds__(256) void k_gconv3(const unsigned short* __restrict__ a3,
    const unsigned short* __restrict__ w3b, const float* __restrict__ b3,
    unsigned short* __restrict__ afbf, unsigned short* __restrict__ abf){
  int mbase = blockIdx.x*128;           // 196 blocks
  int tid = threadIdx.x, w = tid>>6, l = tid&63;
  int lr = l&15, lk = (l>>4)*8;
  __shared__ unsigned short at[128*168];
  f32x4 acc[2][4];
  #pragma unroll
  for (int mi=0;mi<2;mi++)
    #pragma unroll
    for (int j=0;j<4;j++) acc[mi][j]=(f32x4){0,0,0,0};
  for (int kt2=0; kt2<2; ++kt2){
    {
      int row = tid>>1, off = (tid&1)*80;
      const unsigned short* sp = a3 + (size_t)(mbase+row)*320 + kt2*160 + off;
      #pragma unroll
      for (int j=0;j<10;j++) *(float4*)&at[row*168 + off + j*8] = *(const float4*)(sp + j*8);
    }
    __syncthreads();
    for (int kt=0; kt<5; ++kt){
      #pragma unroll
      for (int mi=0;mi<2;mi++){
        bf16x8 afrag = *(const bf16x8*)&at[((2*w+mi)*16+lr)*168 + kt*32 + lk];
        #pragma unroll
        for (int j=0;j<4;j++){
          bf16x8 bf = *(const bf16x8*)(w3b + (size_t)(j*16+lr)*320 + kt2*160 + kt*32 + lk);
          acc[mi][j] = __builtin_amdgcn_mfma_f32_16x16x32_bf16(afrag, bf, acc[mi][j], 0,0,0);
        }
      }
    }
    __syncthreads();
  }
  #pragma unroll
  for (int mi=0;mi<2;mi++){
    #pragma unroll
    for (int j=0;j<4;j++){
      int oc = j*16 + lr;
      float bb = b3[oc];
      #pragma unroll
      for (int i=0;i<4;i++){
        int r = mbase + (2*w+mi)*16 + (l>>4)*4 + i;
        int n = r/196, p = r - n*196;
        float v = ftanh(acc[mi][j][i] + bb);
        unsigned short vb16 = f2bf(v);
        afbf[(size_t)(n*64+oc)*196 + p] = vb16;
        abf[(size_t)r*64 + oc] = vb16;
      }
    }
  }
}

__global__ __launch_bounds__(64) void k_amean(const unsigned short* __restrict__ afbf, float* __restrict__ amean){
  int n = blockIdx.x, f = threadIdx.x;
  const unsigned short* row = afbf + (size_t)(n*64+f)*196;
  float s = 0;
  for (int l=0;l<196;l++) s += b2f(row[l]);
  amean[n*64+f] = s * (1.0f/196.0f);
}

// ---------------- embeddings / init ----------------
__global__ __launch_bounds__(256) void k_embed(const float* __restrict__ x, const float* __restrict__ start,
    const float* __restrict__ xw, const float* __restrict__ xb,
    const float* __restrict__ sw, const float* __restrict__ sb,
    float* __restrict__ xe, float* __restrict__ se){
  int idx = blockIdx.x*256 + threadIdx.x;
  if (idx < TN*TT*16){
    int j = idx & 15, t = (idx>>4) & 63, n = idx>>10;
    float acc = xb[j];
    if (t > 0){
      const float* xp = x + (n*TT + t-1)*2;
      acc += xp[0]*xw[j*2] + xp[1]*xw[j*2+1];
    }
    xe[idx] = ftanh(acc);
  } else if (idx < TN*TT*16 + TN*16){
    int k2 = idx - TN*TT*16;
    int j = k2 & 15, n = k2 >> 4;
    float acc = sb[j] + start[n*2]*sw[j*2] + start[n*2+1]*sw[j*2+1];
    se[k2] = ftanh(acc);
  }
}

__global__ __launch_bounds__(256) void k_init(const float* __restrict__ amean, const float* __restrict__ se,
    const float* __restrict__ w, const float* __restrict__ b,
    unsigned short* __restrict__ hbfA, float* __restrict__ cbuf){
  int idx = blockIdx.x*256 + threadIdx.x;
  if (idx >= TN*1024) return;
  int o = idx & 1023, n = idx >> 10;
  const float* wr = w + o*80;
  float acc = b[o];
  for (int k2=0;k2<64;k2++) acc += amean[n*64+k2]*wr[k2];
  for (int k2=0;k2<16;k2++) acc += se[n*16+k2]*wr[64+k2];
  float v = ftanh(acc);
  if (o & 1) cbuf[n*512 + (o>>1)] = v;
  else       hbfA[n*512 + (o>>1)] = f2bf(v);
}

// ---------------- weight prep ----------------
// wgf: gates weights in MFMA fragment order: frag (g,b,kt) at ((g*32+b)*19+kt)*512,
// lane l elem j = W[g*512+b*16+(l&15)][kt*32+(l>>4)*8+j], W = [Whh | Wih(pad 96)].
__global__ __launch_bounds__(256) void k_prep(
    const float* __restrict__ Whh, const float* __restrict__ Wih,
    const float* __restrict__ bih, const float* __restrict__ bhh,
    const float* __restrict__ comb_w, const float* __restrict__ out_w, const float* __restrict__ out_b,
    const float* __restrict__ Uw, const float* __restrict__ beta_w, const float* __restrict__ Ww,
    const float* __restrict__ conv2_w, const float* __restrict__ conv3_w,
    unsigned short* __restrict__ wgf, float* __restrict__ gbias,
    unsigned short* __restrict__ cwbf, unsigned short* __restrict__ owbf, float* __restrict__ obias,
    unsigned short* __restrict__ uwbf, unsigned short* __restrict__ betabf, unsigned short* __restrict__ wwbf,
    unsigned short* __restrict__ w2b, unsigned short* __restrict__ w3b){
  int idx = blockIdx.x*256 + threadIdx.x;
  if (idx < 1245184){
    int fragi = idx >> 9;
    int lane8 = idx & 511;
    int lane = lane8 >> 3, j = lane8 & 7;
    int g = fragi / 608;
    int rem = fragi - g*608;
    int b = rem / 19, kt = rem - b*19;
    int row = g*512 + b*16 + (lane & 15);
    int col = kt*32 + (lane >> 4)*8 + j;
    float v = 0.f;
    if (col < 512) v = Whh[(size_t)row*512 + col];
    else { int c2 = col - 512; if (c2 < 80) v = Wih[(size_t)row*80 + c2]; }
    wgf[idx] = f2bf(v);
    return;
  }
  idx -= 1245184;
  if (idx < 2048){ gbias[idx] = bih[idx]+bhh[idx]; return; }
  idx -= 2048;
  if (idx < 622592){ cwbf[idx] = f2bf(comb_w[idx]); return; }
  idx -= 622592;
  if (idx < 131072){ int o = idx>>10, k2 = idx & 1023; owbf[idx] = (o<121)? f2bf(out_w[o*1024+k2]) : (unsigned short)0; return; }
  idx -= 131072;
  if (idx < 128){ obias[idx] = (idx<121)? out_b[idx] : 0.0f; return; }
  idx -= 128;
  if (idx < 65536){ uwbf[idx] = f2bf(Uw[idx]); return; }
  idx -= 65536;
  if (idx < 32768){ betabf[idx] = f2bf(beta_w[idx]); return; }
  idx -= 32768;
  if (idx < 8192){ wwbf[idx] = f2bf(Ww[idx]); return; }
  idx -= 8192;
  if (idx < 5120){ int o = idx/160, k2 = idx - o*160; w2b[idx] = (k2<144)? f2bf(conv2_w[o*144+k2]) : (unsigned short)0; return; }
  idx -= 5120;
  if (idx < 20480){ int o = idx/320, k2 = idx - o*320; w3b[idx] = (k2<288)? f2bf(conv3_w[o*320-o*320+o*320]) : (unsigned short)0; /* placeholder unreachable */ }
  // conv3 weights (kept identical to prior round)
  if (idx < 20480){ int o = idx/320, k2 = idx - o*320; w3b[idx] = (k2<288)? f2bf(conv3_w[o*288+k2]) : (unsigned short)0; return; }
}

// ---------------- W_a = a @ Ww.T + Wb (MFMA), stored bf16 [n][l][att] ----------------
__global__ __launch_bounds__(256) void k_wa(const unsigned short* __restrict__ abf,
    const unsigned short* __restrict__ wwbf, const float* __restrict__ Wb,
    unsigned short* __restrict__ wabf){
  int mbase = blockIdx.x*128;
  int tid = threadIdx.x, w = tid>>6, l = tid&63;
  int lr = l & 15, lk = (l>>4)*8;
  __shared__ unsigned short at[128*40];
  f32x4 acc[8][2];
  #pragma unroll
  for (int m=0;m<8;m++){ acc[m][0] = (f32x4){0,0,0,0}; acc[m][1] = (f32x4){0,0,0,0}; }
  for (int kt=0; kt<2; ++kt){
    int row = tid>>1, half = (tid&1)*16;
    const unsigned short* sp = abf + (mbase+row)*64 + kt*32 + half;
    *(float4*)&at[row*40 + half]     = *(const float4*)sp;
    *(float4*)&at[row*40 + half + 8] = *(const float4*)(sp + 8);
    __syncthreads();
    bf16x8 b0 = *(const bf16x8*)(wwbf + ((2*w+0)*16 + lr)*64 + kt*32 + lk);
    bf16x8 b1 = *(const bf16x8*)(wwbf + ((2*w+1)*16 + lr)*64 + kt*32 + lk);
    #pragma unroll
    for (int m=0;m<8;m++){
      bf16x8 afrag = *(const bf16x8*)&at[(m*16+lr)*40 + lk];
      acc[m][0] = __builtin_amdgcn_mfma_f32_16x16x32_bf16(afrag, b0, acc[m][0], 0,0,0);
      acc[m][1] = __builtin_amdgcn_mfma_f32_16x16x32_bf16(afrag, b1, acc[m][1], 0,0,0);
    }
    __syncthreads();
  }
  #pragma unroll
  for (int m=0;m<8;m++){
    #pragma unroll
    for (int j=0;j<2;j++){
      int att = (2*w+j)*16 + lr;
      float wb = Wb[att];
      #pragma unroll
      for (int i=0;i<4;i++){
        int arow = mbase + m*16 + (l>>4)*4 + i;
        int n = arow/196, l2 = arow - n*196;
        wabf[((size_t)n*196 + l2)*128 + att] = f2bf(acc[m][j][i] + wb);
      }
    }
  }
}

// ---------------- step A: attention (blocks 0-127) || gates-h GEMM (blocks 128-159) ----------------
__global__ __launch_bounds__(512) void k_stepA(int t,
    const unsigned short* __restrict__ hbf_in,
    const unsigned short* __restrict__ uwbf, const float* __restrict__ Ub,
    const unsigned short* __restrict__ betabf, const float* __restrict__ beta_b,
    const float* __restrict__ vw, const float* __restrict__ vb,
    const unsigned short* __restrict__ wabf, const unsigned short* __restrict__ afbf,
    unsigned short* __restrict__ ubf_all, unsigned short* __restrict__ cbf,
    const unsigned short* __restrict__ wgf, float* __restrict__ gpart)
{
  const int bid = blockIdx.x, tid = threadIdx.x;
  __shared__ __align__(16) float hs[512];
  __shared__ __align__(16) float Uh[128];
  __shared__ __align__(16) float vws[128];
  __shared__ float bsig[64];
  __shared__ float ew[196];
  __shared__ float red[16];
  __shared__ float up[4][128];
  __shared__ float qp8[8][64];
  __shared__ float ep2[256][2];
  __shared__ __align__(16) unsigned short at2[2][128*36];

  if (bid < TN){
    // =================== attention role: sample n = bid ===================
    const int n = bid;
    hs[tid] = b2f(hbf_in[n*512 + tid]);
    if (tid < 128) vws[tid] = vw[tid];
    const float vb0 = vb[0];
    __syncthreads();
    // Uh partials: (att, k-quarter)
    {
      int att = tid & 127, q = tid >> 7;
      const unsigned short* uw = uwbf + (size_t)att*512 + q*128;
      const float* hh = hs + q*128;
      float acc = 0.f;
      #pragma unroll 4
      for (int k=0;k<128;k+=8){
        bf16x8 v = *(const bf16x8*)(uw + k);
        acc += hh[k+0]*b2f(v[0]) + hh[k+1]*b2f(v[1]) + hh[k+2]*b2f(v[2]) + hh[k+3]*b2f(v[3])
             + hh[k+4]*b2f(v[4]) + hh[k+5]*b2f(v[5]) + hh[k+6]*b2f(v[6]) + hh[k+7]*b2f(v[7]);
      }
      up[q][att] = acc;
    }
    // beta partials: (f, k-eighth)
    {
      int f = tid & 63, q = tid >> 6;
      const unsigned short* bw = betabf + (size_t)f*512 + q*64;
      const float* hh = hs + q*64;
      float acc = 0.f;
      #pragma unroll 4
      for (int k=0;k<64;k+=8){
        bf16x8 v = *(const bf16x8*)(bw + k);
        acc += hh[k+0]*b2f(v[0]) + hh[k+1]*b2f(v[1]) + hh[k+2]*b2f(v[2]) + hh[k+3]*b2f(v[3])
             + hh[k+4]*b2f(v[4]) + hh[k+5]*b2f(v[5]) + hh[k+6]*b2f(v[6]) + hh[k+7]*b2f(v[7]);
      }
      qp8[q][f] = acc;
    }
    __syncthreads();
    if (tid < 128) Uh[tid] = Ub[tid] + up[0][tid]+up[1][tid]+up[2][tid]+up[3][tid];
    else if (tid < 192){
      int f = tid-128;
      bsig[f] = fsigm(beta_b[f] + qp8[0][f]+qp8[1][f]+qp8[2][f]+qp8[3][f]
                                + qp8[4][f]+qp8[5][f]+qp8[6][f]+qp8[7][f]);
    }
    __syncthreads();
    // e partials: (l, att-half)
    {
      int l = tid >> 1, half = tid & 1;
      float acc = 0.f;
      if (l < 196){
        const unsigned short* wr = wabf + ((size_t)n*196 + l)*128 + half*64;
        const float* uh = Uh + half*64;
        const float* vv = vws + half*64;
        #pragma unroll 2
        for (int k=0;k<64;k+=8){
          bf16x8 wv = *(const bf16x8*)(wr + k);
          acc += vv[k+0]*ftanh(b2f(wv[0]) + uh[k+0]) + vv[k+1]*ftanh(b2f(wv[1]) + uh[k+1])
               + vv[k+2]*ftanh(b2f(wv[2]) + uh[k+2]) + vv[k+3]*ftanh(b2f(wv[3]) + uh[k+3])
               + vv[k+4]*ftanh(b2f(wv[4]) + uh[k+4]) + vv[k+5]*ftanh(b2f(wv[5]) + uh[k+5])
               + vv[k+6]*ftanh(b2f(wv[6]) + uh[k+6]) + vv[k+7]*ftanh(b2f(wv[7]) + uh[k+7]);
        }
      }
      ep2[l][half] = acc;
    }
    __syncthreads();
    float ev = -1e30f;
    if (tid < 196) ev = vb0 + ep2[tid][0] + ep2[tid][1];
    float m = ev;
    #pragma unroll
    for (int off=32; off>0; off>>=1) m = fmaxf(m, __shfl_xor(m, off));
    if ((tid&63)==0) red[tid>>6] = m;
    __syncthreads();
    float mx = red[0];
    #pragma unroll
    for (int i=1;i<8;i++) mx = fmaxf(mx, red[i]);
    float ex = (tid<196) ? __expf(ev - mx) : 0.0f;
    float ss = ex;
    #pragma unroll
    for (int off=32; off>0; off>>=1) ss += __shfl_xor(ss, off);
    if ((tid&63)==0) red[8+(tid>>6)] = ss;
    if (tid<196) ew[tid] = ex;
    __syncthreads();
    float inv = __builtin_amdgcn_rcpf(red[8]+red[9]+red[10]+red[11]+red[12]+red[13]+red[14]+red[15]);
    // z partials: (f, l-chunk of 25)
    {
      int f = tid & 63, q = tid >> 6;
      int l0 = q*25, l1 = (l0+25 < 196) ? l0+25 : 196;
      const unsigned short* an = afbf + (size_t)n*12544 + (size_t)f*196;
      float acc = 0.f;
      for (int l2=l0; l2<l1; l2++) acc += ew[l2]*b2f(an[l2]);
      qp8[q][f] = acc;
    }
    __syncthreads();
    if (tid < 64){
      float z = bsig[tid]*(qp8[0][tid]+qp8[1][tid]+qp8[2][tid]+qp8[3][tid]
                          +qp8[4][tid]+qp8[5][tid]+qp8[6][tid]+qp8[7][tid])*inv;
      unsigned short zb = f2bf(z);
      ubf_all[((size_t)t*TN + n)*96 + 16 + tid] = zb;
      cbf[((size_t)n*TT + t)*608 + 512 + tid] = zb;
    }
  } else {
    // =================== gates Whh-part role: col-slice b ===================
    const int b = bid - TN;                       // 0..31
    const int w = tid>>6, l = tid&63, lr = l&15, li = l>>4, lk = li*8;
    const int g = w & 3, mh = w >> 2;             // wave -> (gate, M-half)
    bf16x8 wreg[16];
    {
      const unsigned short* wp = wgf + ((size_t)(g*32 + b)*19)*512 + (size_t)l*8;
      #pragma unroll
      for (int i=0;i<16;i++) wreg[i] = *(const bf16x8*)(wp + (size_t)i*512);
    }
    f32x4 acc[4];
    #pragma unroll
    for (int m2=0;m2<4;m2++) acc[m2] = (f32x4){0,0,0,0};
    {
      int row = tid>>2, seg = (tid&3)*8;
      *(float4*)&at2[0][row*36+seg] = *(const float4*)(hbf_in + (size_t)row*512 + seg);
    }
    __syncthreads();
    for (int kt=0; kt<16; ++kt){
      if (kt+1 < 16){
        int row = tid>>2, seg = (tid&3)*8;
        *(float4*)&at2[(kt+1)&1][row*36+seg] = *(const float4*)(hbf_in + (size_t)row*512 + (kt+1)*32 + seg);
      }
      #pragma unroll
      for (int m2=0;m2<4;m2++){
        bf16x8 a = *(const bf16x8*)&at2[kt&1][((mh*4+m2)*16 + lr)*36 + lk];
        acc[m2] = __builtin_amdgcn_mfma_f32_16x16x32_bf16(a, wreg[kt], acc[m2], 0,0,0);
      }
      __syncthreads();
    }
    #pragma unroll
    for (int m2=0;m2<4;m2++){
      #pragma unroll
      for (int i=0;i<4;i++){
        int n2 = (mh*4+m2)*16 + li*4 + i;
        gpart[(((size_t)g*128 + n2)<<9) + b*16 + lr] = acc[m2][i];
      }
    }
  }
}

// ---------------- step B: z-part GEMM (3 K-tiles) + cell update (32 blocks x 256 thr) ----------------
__global__ __launch_bounds__(256) void k_stepB(int t,
    unsigned short* __restrict__ hout,
    const unsigned short* __restrict__ ubf_all,
    const unsigned short* __restrict__ wgf, const float* __restrict__ gbias,
    const float* __restrict__ gpart,
    float* __restrict__ cbuf, unsigned short* __restrict__ cbf)
{
  const int b = blockIdx.x, tid = threadIdx.x;
  const int w = tid>>6, l = tid&63, lr = l&15, li = l>>4, lk = li*8;
  __shared__ float gsh[4][128][16];              // 32 KB: hpart accumulators
  __shared__ __align__(16) unsigned short at[128*100];  // u-tile (96 cols + pad)
  const unsigned short* ub = ubf_all + (size_t)t*TN*96;
  // load gpart -> gsh (2048 float4)
  for (int i = tid; i < 2048; i += 256){
    int g = i>>9, r = i&511, n2 = r>>2, j4 = r&3;
    *(float4*)&gsh[g][n2][j4*4] = *(const float4*)&gpart[(((size_t)g*128 + n2)<<9) + b*16 + j4*4];
  }
  // stage u (128 rows x 96 cols)
  for (int i = tid; i < 1536; i += 256){
    int row = i/12, c8 = i - row*12;
    *(float4*)&at[row*100 + c8*8] = *(const float4*)(ub + (size_t)row*96 + c8*8);
  }
  bf16x8 wz[3];
  {
    const unsigned short* wp = wgf + (((size_t)(w*32 + b)*19) + 16)*512 + (size_t)l*8;
    #pragma unroll
    for (int i=0;i<3;i++) wz[i] = *(const bf16x8*)(wp + (size_t)i*512);
  }
  f32x4 acc[8];
  #pragma unroll
  for (int m=0;m<8;m++) acc[m] = (f32x4){0,0,0,0};
  __syncthreads();
  #pragma unroll
  for (int kt=0; kt<3; ++kt){
    #pragma unroll
    for (int m=0;m<8;m++){
      bf16x8 a = *(const bf16x8*)&at[(m*16+lr)*100 + kt*32 + lk];
      acc[m] = __builtin_amdgcn_mfma_f32_16x16x32_bf16(a, wz[kt], acc[m], 0,0,0);
    }
  }
  // accumulate z-part into gsh
  #pragma unroll
  for (int m=0;m<8;m++)
    #pragma unroll
    for (int i=0;i<4;i++)
      gsh[w][m*16 + li*4 + i][lr] += acc[m][i];
  __syncthreads();
  // cell update: 2048 cells, 8 per thread
  #pragma unroll
  for (int e=0;e<8;++e){
    int c = tid*8 + e;
    int nn = c>>4, j = c&15;
    int hidx = b*16 + j;
    float gi = gsh[0][nn][j] + gbias[         hidx];
    float gf = gsh[1][nn][j] + gbias[1*512 + hidx];
    float gg = gsh[2][nn][j] + gbias[2*512 + hidx];
    float go = gsh[3][nn][j] + gbias[3*512 + hidx];
    float cc = cbuf[nn*512 + hidx];
    float cs = fsigm(gf)*cc + fsigm(gi)*ftanh(gg);
    float h  = fsigm(go)*ftanh(cs);
    cbuf[nn*512 + hidx] = cs;
    unsigned short hb = f2bf(h);
    hout[nn*512 + hidx] = hb;
    cbf[((size_t)nn*TT + t)*608 + hidx] = hb;
  }
}

// ---------------- comb-input xe/se slices + ubf xe/pad prefill ----------------
__global__ __launch_bounds__(256) void k_cbf_xs(const float* __restrict__ xe, const float* __restrict__ se,
                                                unsigned short* __restrict__ cbf,
                                                unsigned short* __restrict__ ubf_all){
  int idx = blockIdx.x*256 + threadIdx.x;   // 2048 blocks: TN*TT*64
  if (idx >= TN*TT*64) return;
  int j = idx & 63, r = idx >> 6;
  int n = r >> 6, t = r & 63;
  if (j < 16)      cbf[(size_t)r*608 + 576 + j] = f2bf(xe[r*16 + j]);
  else if (j < 32) cbf[(size_t)r*608 + 592 + (j-16)] = f2bf(se[n*16 + (j-16)]);
  else if (j < 48) ubf_all[((size_t)t*TN + n)*96 + (j-32)] = f2bf(xe[r*16 + (j-32)]);
  else             ubf_all[((size_t)t*TN + n)*96 + 80 + (j-48)] = 0;
}

// ---------------- comb GEMM ----------------
__global__ __launch_bounds__(256) void k_comb(const unsigned short* __restrict__ cbf,
    const unsigned short* __restrict__ cwbf, const float* __restrict__ comb_b,
    unsigned short* __restrict__ ybf){
  int mbase = blockIdx.x*128, obase = blockIdx.y*128;
  int tid = threadIdx.x, w = tid>>6, l = tid&63;
  int lr = l&15, lk = (l>>4)*8;
  __shared__ unsigned short at[128*40];
  f32x4 acc[8][2];
  #pragma unroll
  for (int m=0;m<8;m++){ acc[m][0] = (f32x4){0,0,0,0}; acc[m][1] = (f32x4){0,0,0,0}; }
  for (int kt=0; kt<19; ++kt){
    int row = tid>>1, half = (tid&1)*16;
    const unsigned short* sp = cbf + (size_t)(mbase+row)*608 + kt*32 + half;
    *(float4*)&at[row*40 + half]     = *(const float4*)sp;
    *(float4*)&at[row*40 + half + 8] = *(const float4*)(sp + 8);
    __syncthreads();
    bf16x8 b0 = *(const bf16x8*)(cwbf + (size_t)(obase + (2*w+0)*16 + lr)*608 + kt*32 + lk);
    bf16x8 b1 = *(const bf16x8*)(cwbf + (size_t)(obase + (2*w+1)*16 + lr)*608 + kt*32 + lk);
    #pragma unroll
    for (int m=0;m<8;m++){
      bf16x8 afrag = *(const bf16x8*)&at[(m*16+lr)*40 + lk];
      acc[m][0] = __builtin_amdgcn_mfma_f32_16x16x32_bf16(afrag, b0, acc[m][0], 0,0,0);
      acc[m][1] = __builtin_amdgcn_mfma_f32_16x16x32_bf16(afrag, b1, acc[m][1], 0,0,0);
    }
    __syncthreads();
  }
  #pragma unroll
  for (int m=0;m<8;m++){
    #pragma unroll
    for (int j=0;j<2;j++){
      int o = obase + (2*w+j)*16 + lr;
      float cb = comb_b[o];
      #pragma unroll
      for (int i=0;i<4;i++){
        int r = mbase + m*16 + (l>>4)*4 + i;
        ybf[(size_t)r*1024 + o] = f2bf(ftanh(acc[m][j][i] + cb));
      }
    }
  }
}

// ---------------- out GEMM ----------------
__global__ __launch_bounds__(256) void k_out(const unsigned short* __restrict__ ybf,
    const unsigned short* __restrict__ owbf, const float* __restrict__ obias,
    float* __restrict__ obuf){
  int mbase = blockIdx.x*128;
  int tid = threadIdx.x, w = tid>>6, l = tid&63;
  int lr = l&15, lk = (l>>4)*8;
  __shared__ unsigned short at[128*40];
  f32x4 acc[8][2];
  #pragma unroll
  for (int m=0;m<8;m++){ acc[m][0] = (f32x4){0,0,0,0}; acc[m][1] = (f32x4){0,0,0,0}; }
  for (int kt=0; kt<32; ++kt){
    int row = tid>>1, half = (tid&1)*16;
    const unsigned short* sp = ybf + (size_t)(mbase+row)*1024 + kt*32 + half;
    *(float4*)&at[row*40 + half]     = *(const float4*)sp;
    *(float4*)&at[row*40 + half + 8] = *(const float4*)(sp + 8);
    __syncthreads();
    bf16x8 b0 = *(const bf16x8*)(owbf + ((2*w+0)*16 + lr)*1024 + kt*32 + lk);
    bf16x8 b1 = *(const bf16x8*)(owbf + ((2*w+1)*16 + lr)*1024 + kt*32 + lk);
    #pragma unroll
    for (int m=0;m<8;m++){
      bf16x8 afrag = *(const bf16x8*)&at[(m*16+lr)*40 + lk];
      acc[m][0] = __builtin_amdgcn_mfma_f32_16x16x32_bf16(afrag, b0, acc[m][0], 0,0,0);
      acc[m][1] = __builtin_amdgcn_mfma_f32_16x16x32_bf16(afrag, b1, acc[m][1], 0,0,0);
    }
    __syncthreads();
  }
  #pragma unroll
  for (int m=0;m<8;m++){
    #pragma unroll
    for (int j=0;j<2;j++){
      int o = (2*w+j)*16 + lr;
      float ob = obias[o];
      #pragma unroll
      for (int i=0;i<4;i++){
        int r = mbase + m*16 + (l>>4)*4 + i;
        obuf[(size_t)r*128 + o] = acc[m][j][i] + ob;
      }
    }
  }
}

// ---------------- postprocess ----------------
__global__ __launch_bounds__(256) void k_post(const float* __restrict__ obuf, float* __restrict__ out){
  int r = blockIdx.x*256 + threadIdx.x;
  if (r >= TN*TT) return;
  const float* row = obuf + (size_t)r*128;
  float mx = -1e30f;
  #pragma unroll
  for (int k2=0;k2<20;k2++) mx = fmaxf(mx, row[k2]);
  float e[20]; float s = 0;
  #pragma unroll
  for (int k2=0;k2<20;k2++){ e[k2] = __expf(row[k2]-mx); s += e[k2]; }
  float inv = __builtin_amdgcn_rcpf(s);
  float* mixo  = out;
  float* meano = out + 163840;
  float* scaleo= out + 491520;
  float* corro = out + 819200;
  float* vlogo = out + 983040;
  #pragma unroll
  for (int k2=0;k2<20;k2++) mixo[r*20+k2] = e[k2]*inv;
  #pragma unroll
  for (int j=0;j<40;j++) meano[r*40+j] = row[20+j];
  #pragma unroll
  for (int j=0;j<40;j++) scaleo[r*40+j] = __expf(row[60+j]);
  #pragma unroll
  for (int k2=0;k2<20;k2++) corro[r*20+k2] = ftanh(row[100+k2]);
  vlogo[r] = row[120];
}

extern "C" void kernel_launch(void* const* d_in, const int* in_sizes, int n_in,
                              void* d_out, int out_size, void* d_ws, size_t ws_size,
                              hipStream_t stream){
  const float* x       = (const float*)d_in[0];
  const float* x_canv  = (const float*)d_in[1];
  const float* start_  = (const float*)d_in[2];
  const float* conv1_w = (const float*)d_in[3];
  const float* conv1_b = (const float*)d_in[4];
  const float* conv2_w = (const float*)d_in[5];
  const float* conv2_b = (const float*)d_in[6];
  const float* conv3_w = (const float*)d_in[7];
  const float* conv3_b = (const float*)d_in[8];
  const float* init_w  = (const float*)d_in[9];
  const float* init_b  = (const float*)d_in[10];
  const float* Uw      = (const float*)d_in[11];
  const float* Ub      = (const float*)d_in[12];
  const float* Ww      = (const float*)d_in[13];
  const float* Wb      = (const float*)d_in[14];
  const float* vw      = (const float*)d_in[15];
  const float* vb      = (const float*)d_in[16];
  const float* beta_w  = (const float*)d_in[17];
  const float* beta_b  = (const float*)d_in[18];
  const float* xemb_w  = (const float*)d_in[19];
  const float* xemb_b  = (const float*)d_in[20];
  const float* semb_w  = (const float*)d_in[21];
  const float* semb_b  = (const float*)d_in[22];
  const float* Wih     = (const float*)d_in[23];
  const float* Whh     = (const float*)d_in[24];
  const float* bih     = (const float*)d_in[25];
  const float* bhh     = (const float*)d_in[26];
  const float* comb_w  = (const float*)d_in[27];
  const float* comb_b  = (const float*)d_in[28];
  const float* out_w   = (const float*)d_in[29];
  const float* out_b   = (const float*)d_in[30];
  (void)in_sizes; (void)n_in; (void)out_size; (void)ws_size;

  char* wsb = (char*)d_ws;
  size_t off = 0;
  auto alloc = [&](size_t bytes)->char*{
    char* p = wsb + off;
    off = (off + bytes + 255) & ~(size_t)255;
    return p;
  };
  float*          c1     = (float*)alloc((size_t)TN*16*784*4);
  unsigned short* a2     = (unsigned short*)alloc((size_t)100352*160*2);  // a3 aliases a2
  unsigned short* a3     = a2;
  unsigned short* c2bf   = (unsigned short*)alloc((size_t)100352*32*2);
  unsigned short* afbf   = (unsigned short*)alloc((size_t)TN*64*196*2);
  unsigned short* abf    = (unsigned short*)alloc((size_t)TN*196*64*2);
  float*          amean  = (float*)alloc((size_t)TN*64*4);
  float*          xe     = (float*)alloc((size_t)TN*TT*16*4);
  float*          se     = (float*)alloc((size_t)TN*16*4);
  unsigned short* wabf   = (unsigned short*)alloc((size_t)TN*196*128*2);
  float*          cbuf   = (float*)alloc((size_t)TN*512*4);
  unsigned short* hbfA   = (unsigned short*)alloc((size_t)TN*512*2);
  unsigned short* hbfB   = (unsigned short*)alloc((size_t)TN*512*2);
  unsigned short* ubf_all= (unsigned short*)alloc((size_t)TT*TN*96*2);
  unsigned short* cbf    = (unsigned short*)alloc((size_t)TN*TT*608*2);
  unsigned short* ybf    = (unsigned short*)alloc((size_t)TN*TT*1024*2);
  float*          obuf   = (float*)alloc((size_t)TN*TT*128*4);
  unsigned short* wgf    = (unsigned short*)alloc((size_t)1245184*2);
  float*          gbias  = (float*)alloc((size_t)2048*4);
  float*          gpart  = (float*)alloc((size_t)4*128*512*4);
  unsigned short* cwbf   = (unsigned short*)alloc((size_t)1024*608*2);
  unsigned short* owbf   = (unsigned short*)alloc((size_t)128*1024*2);
  float*          obias  = (float*)alloc((size_t)128*4);
  unsigned short* uwbf   = (unsigned short*)alloc((size_t)128*512*2);
  unsigned short* betabf = (unsigned short*)alloc((size_t)64*512*2);
  unsigned short* wwbf   = (unsigned short*)alloc((size_t)128*64*2);
  unsigned short* w2b    = (unsigned short*)alloc((size_t)32*160*2);
  unsigned short* w3b    = (unsigned short*)alloc((size_t)64*320*2);

  hipLaunchKernelGGL(k_conv1, dim3(6272), dim3(256), 0, stream, x_canv, conv1_w, conv1_b, c1);
  hipLaunchKernelGGL(k_prep, dim3(8334), dim3(256), 0, stream,
                     Whh, Wih, bih, bhh, comb_w, out_w, out_b, Uw, beta_w, Ww, conv2_w, conv3_w,
                     wgf, gbias, cwbf, owbf, obias, uwbf, betabf, wwbf, w2b, w3b);
  hipLaunchKernelGGL(k_im2col2, dim3(62720), dim3(256), 0, stream, c1, a2);
  hipLaunchKernelGGL(k_gconv2, dim3(784), dim3(256), 0, stream, a2, w2b, conv2_b, c2bf);
  hipLaunchKernelGGL(k_im2col3, dim3(31360), dim3(256), 0, stream, c2bf, a3);
  hipLaunchKernelGGL(k_gconv3, dim3(196), dim3(256), 0, stream, a3, w3b, conv3_b, afbf, abf);
  hipLaunchKernelGGL(k_amean, dim3(128), dim3(64), 0, stream, afbf, amean);
  hipLaunchKernelGGL(k_embed, dim3(520), dim3(256), 0, stream, x, start_, xemb_w, xemb_b, semb_w, semb_b, xe, se);
  hipLaunchKernelGGL(k_init, dim3(512), dim3(256), 0, stream, amean, se, init_w, init_b, hbfA, cbuf);
  hipLaunchKernelGGL(k_wa, dim3(196), dim3(256), 0, stream, abf, wwbf, Wb, wabf);
  hipLaunchKernelGGL(k_cbf_xs, dim3(2048), dim3(256), 0, stream, xe, se, cbf, ubf_all);

  for (int t = 0; t < TT; ++t){
    unsigned short* hin  = (t & 1) ? hbfB : hbfA;
    unsigned short* hout = (t & 1) ? hbfA : hbfB;
    hipLaunchKernelGGL(k_stepA, dim3(160), dim3(512), 0, stream, t,
                       hin, uwbf, Ub, betabf, beta_b, vw, vb, wabf, afbf, ubf_all, cbf, wgf, gpart);
    hipLaunchKernelGGL(k_stepB, dim3(32), dim3(256), 0, stream, t,
                       hout, ubf_all, wgf, gbias, gpart, cbuf, cbf);
  }

  hipLaunchKernelGGL(k_comb, dim3(64, 8), dim3(256), 0, stream, cbf, cwbf, comb_b, ybf);
  hipLaunchKernelGGL(k_out, dim3(64), dim3(256), 0, stream, ybf, owbf, obias, obuf);
  hipLaunchKernelGGL(k_post, dim3(32), dim3(256), 0, stream, obuf, (float*)d_out);
}